// Round 1
// baseline (342.894 us; speedup 1.0000x reference)
//
#include <hip/hip_runtime.h>

using u16 = unsigned short;
using uch = unsigned char;

typedef __bf16 bf16x8 __attribute__((ext_vector_type(8)));
typedef float f32x4 __attribute__((ext_vector_type(4)));

// ---------- constants ----------
#define BATCH 4
#define SEQN 4096
#define TT 16
#define MM 64
#define DIM 1024
#define HEADS 8
#define DH 64
#define INNER 512
#define KVN 1024
#define NTOK (BATCH*SEQN)          // 16384

// ws offsets (bytes)
#define OFF_XN     ((size_t)0)                     // 16384x1024 bf16 = 32MB
#define OFF_MEDIA  ((size_t)33554432)              // 4096x1024 bf16 = 8MB
#define OFF_Q      ((size_t)41943040)              // 16384x512 bf16 = 16MB
#define OFF_KV     ((size_t)58720256)              // 4096x1024 bf16 = 8MB
#define OFF_AOUT   ((size_t)67108864)              // 16384x512 bf16 = 16MB
#define OFF_WQT    ((size_t)83886080)              // 512x1024 bf16 = 1MB
#define OFF_WKVT   ((size_t)84934656)              // 1024x1024 bf16 = 2MB
#define OFF_WOT    ((size_t)87031808)              // 1024x512 bf16 = 1MB
#define OFF_SEL    ((size_t)88080384)              // 16384 int = 64KB
#define OFF_VSUM   ((size_t)88145920)              // 4x512 f32 = 8KB
#define OFF_FLAGS  ((size_t)88154112)              // int[2]

__device__ __forceinline__ u16 f2bf(float f){
  unsigned int u = __float_as_uint(f);
  u += 0x7fffu + ((u >> 16) & 1u);
  return (u16)(u >> 16);
}
__device__ __forceinline__ float bf2f(u16 b){ return __uint_as_float(((unsigned int)b) << 16); }
__device__ __forceinline__ float bflo(unsigned int u){ return __uint_as_float(u << 16); }
__device__ __forceinline__ float bfhi(unsigned int u){ return __uint_as_float(u & 0xffff0000u); }

__device__ __forceinline__ void async16(const u16* g, void* l){
  __builtin_amdgcn_global_load_lds((__attribute__((address_space(1))) void*)(g),
                                   (__attribute__((address_space(3))) void*)(l), 16, 0, 0);
}

// ---------- format detection ----------
// flags[0]: 1 if float tensors are bf16, 0 if fp32
// flags[1]: 1 if media_locations is int32, 0 if 1-byte (bool)
__global__ void detect_kernel(const unsigned int* __restrict__ x, const uch* __restrict__ loc,
                              int* __restrict__ flags){
  __shared__ int cnt, nonz;
  int tid = threadIdx.x;
  if (tid == 0){ cnt = 0; nonz = 0; }
  __syncthreads();
  int c = 0;
  for (int t = 0; t < 4; ++t){
    unsigned int w = x[t*256 + tid];
    unsigned int e = (w >> 7) & 0xFFu;   // bf16: exponent field of low element; fp32: mid mantissa
    if (e >= 110u && e <= 140u) c++;
  }
  atomicAdd(&cnt, c);
  int nz = 0;
  for (int t = 0; t < 16; ++t){
    int i = t*256 + tid;                 // first 16384 bytes are valid in both layouts
    if ((i & 3) && loc[i]) nz++;
  }
  atomicAdd(&nonz, nz);
  __syncthreads();
  if (tid == 0){ flags[0] = (cnt > 512) ? 1 : 0; flags[1] = (nonz == 0) ? 1 : 0; }
}

// ---------- weight transpose + convert: in [K][N] (fp32 or bf16) -> out [N][K] bf16 ----------
__global__ void wtrans_kernel(const void* __restrict__ in, u16* __restrict__ out, int K, int N,
                              const int* __restrict__ flags){
  const int bf = flags[0];
  __shared__ float tile[32][33];
  int n0 = blockIdx.x*32, k0 = blockIdx.y*32;
  int tx = threadIdx.x, ty = threadIdx.y;
  #pragma unroll
  for (int i = 0; i < 4; ++i){
    size_t idx = (size_t)(k0 + ty + i*8)*N + n0 + tx;
    tile[ty + i*8][tx] = bf ? bf2f(((const u16*)in)[idx]) : ((const float*)in)[idx];
  }
  __syncthreads();
  #pragma unroll
  for (int i = 0; i < 4; ++i)
    out[(size_t)(n0 + ty + i*8)*K + k0 + tx] = f2bf(tile[tx][ty + i*8]);
}

// ---------- LayerNorm -> bf16 ----------
__global__ __launch_bounds__(256) void ln_kernel(const void* __restrict__ xp, const void* __restrict__ gp,
                          const void* __restrict__ bp, u16* __restrict__ xn, const int* __restrict__ flags){
  const int bf = flags[0];
  const int row = blockIdx.x, tid = threadIdx.x;
  float v[4];
  if (bf){
    ushort4 t = ((const ushort4*)((const u16*)xp + (size_t)row*DIM))[tid];
    v[0]=bf2f(t.x); v[1]=bf2f(t.y); v[2]=bf2f(t.z); v[3]=bf2f(t.w);
  } else {
    float4 t = ((const float4*)((const float*)xp + (size_t)row*DIM))[tid];
    v[0]=t.x; v[1]=t.y; v[2]=t.z; v[3]=t.w;
  }
  float s = v[0]+v[1]+v[2]+v[3];
  float sq = v[0]*v[0]+v[1]*v[1]+v[2]*v[2]+v[3]*v[3];
  #pragma unroll
  for (int o = 32; o > 0; o >>= 1){ s += __shfl_down(s, o); sq += __shfl_down(sq, o); }
  __shared__ float ss[4], ssq[4];
  int wid = tid >> 6, lane = tid & 63;
  if (lane == 0){ ss[wid] = s; ssq[wid] = sq; }
  __syncthreads();
  s = ss[0]+ss[1]+ss[2]+ss[3]; sq = ssq[0]+ssq[1]+ssq[2]+ssq[3];
  float mean = s * (1.f/DIM);
  float rstd = rsqrtf(sq * (1.f/DIM) - mean*mean + 1e-5f);
  float g[4], bb[4];
  if (bf){
    ushort4 t1 = ((const ushort4*)gp)[tid]; ushort4 t2 = ((const ushort4*)bp)[tid];
    g[0]=bf2f(t1.x); g[1]=bf2f(t1.y); g[2]=bf2f(t1.z); g[3]=bf2f(t1.w);
    bb[0]=bf2f(t2.x); bb[1]=bf2f(t2.y); bb[2]=bf2f(t2.z); bb[3]=bf2f(t2.w);
  } else {
    float4 t1 = ((const float4*)gp)[tid]; float4 t2 = ((const float4*)bp)[tid];
    g[0]=t1.x; g[1]=t1.y; g[2]=t1.z; g[3]=t1.w;
    bb[0]=t2.x; bb[1]=t2.y; bb[2]=t2.z; bb[3]=t2.w;
  }
  ushort4 o;
  o.x = f2bf((v[0]-mean)*rstd*g[0] + bb[0]);
  o.y = f2bf((v[1]-mean)*rstd*g[1] + bb[1]);
  o.z = f2bf((v[2]-mean)*rstd*g[2] + bb[2]);
  o.w = f2bf((v[3]-mean)*rstd*g[3] + bb[3]);
  ((ushort4*)(xn + (size_t)row*DIM))[tid] = o;
}

// ---------- media fp32/bf16 -> bf16 ----------
__global__ __launch_bounds__(256) void cvt_kernel(const void* __restrict__ in, u16* __restrict__ out,
                           const int* __restrict__ flags){
  const int bf = flags[0];
  size_t i = (size_t)blockIdx.x*256 + threadIdx.x;  // 4 elems per thread
  if (bf){
    ((ushort4*)out)[i] = ((const ushort4*)in)[i];
  } else {
    float4 t = ((const float4*)in)[i];
    ushort4 o; o.x = f2bf(t.x); o.y = f2bf(t.y); o.z = f2bf(t.z); o.w = f2bf(t.w);
    ((ushort4*)out)[i] = o;
  }
}

// ---------- cumsum of media_locations -> sel (media index or -1) ----------
__global__ __launch_bounds__(256) void cumsum_kernel(const void* __restrict__ locp, int* __restrict__ sel,
                              const int* __restrict__ flags){
  const int as32 = flags[1];
  int b = blockIdx.x, tid = threadIdx.x;
  int lane = tid & 63, wid = tid >> 6;
  __shared__ int wsum[4]; __shared__ int carry;
  if (tid == 0) carry = 0;
  __syncthreads();
  for (int t = 0; t < 16; ++t){
    int idx = t*256 + tid;
    int v;
    if (as32) v = (((const int*)locp)[b*SEQN + idx] != 0);
    else      v = (((const uch*)locp)[b*SEQN + idx] != 0);
    int s = v;
    #pragma unroll
    for (int o = 1; o < 64; o <<= 1){ int n = __shfl_up(s, o); if (lane >= o) s += n; }
    if (lane == 63) wsum[wid] = s;
    __syncthreads();
    int wo = carry;
    for (int w = 0; w < wid; ++w) wo += wsum[w];
    int tt = wo + s;
    sel[b*SEQN + idx] = (tt >= 1 && tt <= TT) ? (tt - 1) : -1;
    __syncthreads();
    if (tid == 0) carry += wsum[0] + wsum[1] + wsum[2] + wsum[3];
    __syncthreads();
  }
}

// ---------- zero ----------
__global__ void zero_kernel(float* __restrict__ p, int n){
  int i = blockIdx.x*256 + threadIdx.x;
  if (i < n) p[i] = 0.f;
}

// ---------- V column sums (for uniform-softmax fallback) ----------
__global__ __launch_bounds__(512) void vsum_kernel(const u16* __restrict__ kv, float* __restrict__ vsum){
  int b = blockIdx.x, ch = blockIdx.y, c = threadIdx.x;
  size_t base = ((size_t)b*KVN + ch*128)*1024 + 512 + c;
  float s = 0.f;
  for (int r = 0; r < 128; ++r) s += bf2f(kv[base + (size_t)r*1024]);
  atomicAdd(&vsum[b*512 + c], s);
}

// ---------- GEMM: C[M,N] = alpha * A[M,K] @ Bt[N,K]^T   (bf16 in, fp32 acc) ----------
// MODE 0: C bf16 always.  MODE 1: C bf16 if flags[0] else fp32.
template<int MODE>
__global__ __launch_bounds__(256) void gemm_bt(const u16* __restrict__ A, const u16* __restrict__ Bt,
                        void* __restrict__ Cp, int M, int N, int K, float alpha,
                        const int* __restrict__ flags){
  __shared__ u16 As[128*64];
  __shared__ u16 Bs[128*64];
  const int tid = threadIdx.x, wid = tid >> 6, lane = tid & 63;
  const int rm = blockIdx.x, rn = blockIdx.y;
  const int wr = wid >> 1, wc = wid & 1;
  const int lr = lane & 15, lg = lane >> 4;
  f32x4 acc[4][4] = {};
  const u16* Ab = A + (size_t)rm*128*K;
  const u16* Bb = Bt + (size_t)rn*128*K;
  for (int k0 = 0; k0 < K; k0 += 64){
    __syncthreads();
    #pragma unroll
    for (int t = 0; t < 4; ++t){
      int c = t*256 + tid;
      int row = c >> 3;
      int qs = (c & 7) ^ (row & 7);          // XOR-swizzled source so LDS stays linear
      int ldsOff = (t*256 + wid*64) * 16;
      async16(Ab + (size_t)row*K + k0 + qs*8, (char*)As + ldsOff);
      async16(Bb + (size_t)row*K + k0 + qs*8, (char*)Bs + ldsOff);
    }
    __syncthreads();
    #pragma unroll
    for (int ks = 0; ks < 2; ++ks){
      bf16x8 af[4], bfr[4];
      #pragma unroll
      for (int m = 0; m < 4; ++m){
        int row = wr*64 + m*16 + lr;
        int q = (ks*4 + lg) ^ (row & 7);
        af[m] = *(const bf16x8*)((const char*)As + row*128 + (q << 4));
      }
      #pragma unroll
      for (int n = 0; n < 4; ++n){
        int row = wc*64 + n*16 + lr;
        int q = (ks*4 + lg) ^ (row & 7);
        bfr[n] = *(const bf16x8*)((const char*)Bs + row*128 + (q << 4));
      }
      #pragma unroll
      for (int m = 0; m < 4; ++m)
        #pragma unroll
        for (int n = 0; n < 4; ++n)
          acc[m][n] = __builtin_amdgcn_mfma_f32_16x16x32_bf16(af[m], bfr[n], acc[m][n], 0, 0, 0);
    }
  }
  const bool obf = (MODE == 0) || (flags[0] != 0);
  #pragma unroll
  for (int m = 0; m < 4; ++m){
    #pragma unroll
    for (int n = 0; n < 4; ++n){
      int row0 = rm*128 + wr*64 + m*16 + lg*4;
      int col  = rn*128 + wc*64 + n*16 + lr;
      #pragma unroll
      for (int r = 0; r < 4; ++r){
        float v = acc[m][n][r] * alpha;
        size_t idx = (size_t)(row0 + r)*N + col;
        if (obf) ((u16*)Cp)[idx] = f2bf(v);
        else     ((float*)Cp)[idx] = v;
      }
    }
  }
}

// ---------- masked attention: one wave per token ----------
__global__ __launch_bounds__(256) void attn_kernel(const u16* __restrict__ q, const u16* __restrict__ kv,
                        const int* __restrict__ sel, const float* __restrict__ vsum,
                        u16* __restrict__ aout){
  const int wid = threadIdx.x >> 6, lane = threadIdx.x & 63;
  const int token = blockIdx.x*4 + wid;
  const int b = token >> 12;
  const int s = sel[token];
  u16* orow = aout + (size_t)token*INNER;
  if (s < 0){
    // uniform softmax over all KV -> mean of V
    const float4* vs = (const float4*)(vsum + b*512);
    float4 a = vs[lane*2], c = vs[lane*2 + 1];
    const float inv = 1.f/1024.f;
    ushort4 o0, o1;
    o0.x = f2bf(a.x*inv); o0.y = f2bf(a.y*inv); o0.z = f2bf(a.z*inv); o0.w = f2bf(a.w*inv);
    o1.x = f2bf(c.x*inv); o1.y = f2bf(c.y*inv); o1.z = f2bf(c.z*inv); o1.w = f2bf(c.w*inv);
    ((ushort4*)orow)[lane*2] = o0; ((ushort4*)orow)[lane*2 + 1] = o1;
    return;
  }
  const u16* qrow = q + (size_t)token*INNER;
  const size_t kbase = ((size_t)b*KVN + s*MM)*1024;
  for (int h = 0; h < HEADS; ++h){
    // scores: lane j = kv position
    const uint4* krow = (const uint4*)(kv + kbase + (size_t)lane*1024 + h*DH);
    const uint4* qh = (const uint4*)(qrow + h*DH);
    float sc = 0.f;
    #pragma unroll
    for (int c = 0; c < 8; ++c){
      uint4 kb = krow[c], qb = qh[c];
      sc += bflo(kb.x)*bflo(qb.x) + bfhi(kb.x)*bfhi(qb.x);
      sc += bflo(kb.y)*bflo(qb.y) + bfhi(kb.y)*bfhi(qb.y);
      sc += bflo(kb.z)*bflo(qb.z) + bfhi(kb.z)*bfhi(qb.z);
      sc += bflo(kb.w)*bflo(qb.w) + bfhi(kb.w)*bfhi(qb.w);
    }
    float mx = sc;
    #pragma unroll
    for (int o = 32; o > 0; o >>= 1) mx = fmaxf(mx, __shfl_xor(mx, o));
    float p = __expf(sc - mx);
    float sum = p;
    #pragma unroll
    for (int o = 32; o > 0; o >>= 1) sum += __shfl_xor(sum, o);
    p /= sum;
    // PV: lane d = head dim
    const u16* vcol = kv + kbase + 512 + h*DH + lane;
    float outv = 0.f;
    #pragma unroll 8
    for (int j = 0; j < 64; ++j){
      float pj = __shfl(p, j);
      outv += pj * bf2f(vcol[(size_t)j*1024]);
    }
    orow[h*DH + lane] = f2bf(outv);
  }
}

extern "C" void kernel_launch(void* const* d_in, const int* in_sizes, int n_in,
                              void* d_out, int out_size, void* d_ws, size_t ws_size,
                              hipStream_t stream){
  const void* x      = d_in[0];
  const void* media  = d_in[1];
  const void* mloc   = d_in[2];
  const void* ln_g   = d_in[3];
  const void* ln_b   = d_in[4];
  const void* Wq     = d_in[5];
  const void* Wk     = d_in[6];
  const void* Wv     = d_in[7];
  const void* Wo     = d_in[8];
  char* ws = (char*)d_ws;
  u16* xn    = (u16*)(ws + OFF_XN);
  u16* medb  = (u16*)(ws + OFF_MEDIA);
  u16* qb    = (u16*)(ws + OFF_Q);
  u16* kvb   = (u16*)(ws + OFF_KV);
  u16* aout  = (u16*)(ws + OFF_AOUT);
  u16* WqT   = (u16*)(ws + OFF_WQT);
  u16* WkvT  = (u16*)(ws + OFF_WKVT);
  u16* WoT   = (u16*)(ws + OFF_WOT);
  int* sel   = (int*)(ws + OFF_SEL);
  float* vsm = (float*)(ws + OFF_VSUM);
  int* flags = (int*)(ws + OFF_FLAGS);

  detect_kernel<<<1, 256, 0, stream>>>((const unsigned int*)x, (const uch*)mloc, flags);

  dim3 tb(32, 8);
  wtrans_kernel<<<dim3(16, 32), tb, 0, stream>>>(Wq, WqT, DIM, INNER, flags);           // WqT [512][1024]
  wtrans_kernel<<<dim3(16, 32), tb, 0, stream>>>(Wk, WkvT, DIM, INNER, flags);          // rows 0-511
  wtrans_kernel<<<dim3(16, 32), tb, 0, stream>>>(Wv, WkvT + (size_t)512*1024, DIM, INNER, flags); // rows 512-1023
  wtrans_kernel<<<dim3(32, 16), tb, 0, stream>>>(Wo, WoT, INNER, DIM, flags);           // WoT [1024][512]

  zero_kernel<<<8, 256, 0, stream>>>(vsm, BATCH*512);
  ln_kernel<<<NTOK, 256, 0, stream>>>(x, ln_g, ln_b, xn, flags);
  cvt_kernel<<<4096, 256, 0, stream>>>(media, medb, flags);   // 4096*256*4 = 4.19M elems exact
  cumsum_kernel<<<BATCH, 256, 0, stream>>>(mloc, sel, flags);

  // q = (xn @ Wq) * DH^-0.5   [16384, 512]
  gemm_bt<0><<<dim3(128, 4), 256, 0, stream>>>(xn, WqT, qb, NTOK, INNER, DIM, 0.125f, flags);
  // kv = media @ [Wk | Wv]    [4096, 1024]
  gemm_bt<0><<<dim3(32, 8), 256, 0, stream>>>(medb, WkvT, kvb, BATCH*KVN, 1024, DIM, 1.f, flags);

  vsum_kernel<<<dim3(BATCH, 8), 512, 0, stream>>>(kvb, vsm);
  attn_kernel<<<NTOK/4, 256, 0, stream>>>(qb, kvb, sel, vsm, aout);

  // out = aout @ Wo           [16384, 1024], fp32 or bf16 per detected mode
  gemm_bt<1><<<dim3(128, 8), 256, 0, stream>>>(aout, WoT, d_out, NTOK, DIM, INNER, 1.f, flags);
}

// Round 2
// 342.109 us; speedup vs baseline: 1.0023x; 1.0023x over previous
//
#include <hip/hip_runtime.h>

using u16 = unsigned short;
using uch = unsigned char;

typedef __bf16 bf16x8 __attribute__((ext_vector_type(8)));
typedef float f32x4 __attribute__((ext_vector_type(4)));

// ---------- constants ----------
#define BATCH 4
#define SEQN 4096
#define TT 16
#define MM 64
#define DIM 1024
#define HEADS 8
#define DH 64
#define INNER 512
#define KVN 1024
#define NTOK (BATCH*SEQN)          // 16384
#define MAXBLK 324                 // 4 * (64 + 17) upper bound on chunk count

// ws offsets (bytes)
#define OFF_XN     ((size_t)0)                     // 16384x1024 bf16 = 32MB
#define OFF_MEDIA  ((size_t)33554432)              // 4096x1024 bf16 = 8MB
#define OFF_Q      ((size_t)41943040)              // 16384x512 bf16 = 16MB
#define OFF_KV     ((size_t)58720256)              // 4096x1024 bf16 = 8MB
#define OFF_AOUT   ((size_t)67108864)              // 16384x512 bf16 = 16MB
#define OFF_WQT    ((size_t)83886080)              // 512x1024 bf16 = 1MB
#define OFF_WKVT   ((size_t)84934656)              // 1024x1024 bf16 = 2MB
#define OFF_WOT    ((size_t)87031808)              // 1024x512 bf16 = 1MB
#define OFF_SEL    ((size_t)88080384)              // 16384 int = 64KB
#define OFF_VSUM   ((size_t)88145920)              // 4x512 f32 = 8KB
#define OFF_FLAGS  ((size_t)88154112)              // int[2]
#define OFF_VT     ((size_t)88155136)              // 64 groups x 512 x 64 bf16 = 4MB
#define OFF_TOKL   ((size_t)92349440)              // 16384 int = 64KB
#define OFF_CNT    ((size_t)92414976)              // 68 int
#define OFF_CURS   ((size_t)92416000)              // 68 int
#define OFF_OFFS   ((size_t)92417024)              // 68 int
#define OFF_NBLK   ((size_t)92418048)              // int
#define OFF_DESC   ((size_t)92419072)              // MAXBLK x int4 = 5184B

__device__ __forceinline__ u16 f2bf(float f){
  unsigned int u = __float_as_uint(f);
  u += 0x7fffu + ((u >> 16) & 1u);
  return (u16)(u >> 16);
}
__device__ __forceinline__ float bf2f(u16 b){ return __uint_as_float(((unsigned int)b) << 16); }

__device__ __forceinline__ void async16(const u16* g, void* l){
  __builtin_amdgcn_global_load_lds((__attribute__((address_space(1))) void*)(g),
                                   (__attribute__((address_space(3))) void*)(l), 16, 0, 0);
}

// ---------- format detection ----------
__global__ void detect_kernel(const unsigned int* __restrict__ x, const uch* __restrict__ loc,
                              int* __restrict__ flags){
  __shared__ int cnt, nonz;
  int tid = threadIdx.x;
  if (tid == 0){ cnt = 0; nonz = 0; }
  __syncthreads();
  int c = 0;
  for (int t = 0; t < 4; ++t){
    unsigned int w = x[t*256 + tid];
    unsigned int e = (w >> 7) & 0xFFu;
    if (e >= 110u && e <= 140u) c++;
  }
  atomicAdd(&cnt, c);
  int nz = 0;
  for (int t = 0; t < 16; ++t){
    int i = t*256 + tid;
    if ((i & 3) && loc[i]) nz++;
  }
  atomicAdd(&nonz, nz);
  __syncthreads();
  if (tid == 0){ flags[0] = (cnt > 512) ? 1 : 0; flags[1] = (nonz == 0) ? 1 : 0; }
}

// ---------- weight transpose + convert ----------
__global__ void wtrans_kernel(const void* __restrict__ in, u16* __restrict__ out, int K, int N,
                              const int* __restrict__ flags){
  const int bf = flags[0];
  __shared__ float tile[32][33];
  int n0 = blockIdx.x*32, k0 = blockIdx.y*32;
  int tx = threadIdx.x, ty = threadIdx.y;
  #pragma unroll
  for (int i = 0; i < 4; ++i){
    size_t idx = (size_t)(k0 + ty + i*8)*N + n0 + tx;
    tile[ty + i*8][tx] = bf ? bf2f(((const u16*)in)[idx]) : ((const float*)in)[idx];
  }
  __syncthreads();
  #pragma unroll
  for (int i = 0; i < 4; ++i)
    out[(size_t)(n0 + ty + i*8)*K + k0 + tx] = f2bf(tile[tx][ty + i*8]);
}

// ---------- LayerNorm -> bf16 ----------
__global__ __launch_bounds__(256) void ln_kernel(const void* __restrict__ xp, const void* __restrict__ gp,
                          const void* __restrict__ bp, u16* __restrict__ xn, const int* __restrict__ flags){
  const int bf = flags[0];
  const int row = blockIdx.x, tid = threadIdx.x;
  float v[4];
  if (bf){
    ushort4 t = ((const ushort4*)((const u16*)xp + (size_t)row*DIM))[tid];
    v[0]=bf2f(t.x); v[1]=bf2f(t.y); v[2]=bf2f(t.z); v[3]=bf2f(t.w);
  } else {
    float4 t = ((const float4*)((const float*)xp + (size_t)row*DIM))[tid];
    v[0]=t.x; v[1]=t.y; v[2]=t.z; v[3]=t.w;
  }
  float s = v[0]+v[1]+v[2]+v[3];
  float sq = v[0]*v[0]+v[1]*v[1]+v[2]*v[2]+v[3]*v[3];
  #pragma unroll
  for (int o = 32; o > 0; o >>= 1){ s += __shfl_down(s, o); sq += __shfl_down(sq, o); }
  __shared__ float ss[4], ssq[4];
  int wid = tid >> 6, lane = tid & 63;
  if (lane == 0){ ss[wid] = s; ssq[wid] = sq; }
  __syncthreads();
  s = ss[0]+ss[1]+ss[2]+ss[3]; sq = ssq[0]+ssq[1]+ssq[2]+ssq[3];
  float mean = s * (1.f/DIM);
  float rstd = rsqrtf(sq * (1.f/DIM) - mean*mean + 1e-5f);
  float g[4], bb[4];
  if (bf){
    ushort4 t1 = ((const ushort4*)gp)[tid]; ushort4 t2 = ((const ushort4*)bp)[tid];
    g[0]=bf2f(t1.x); g[1]=bf2f(t1.y); g[2]=bf2f(t1.z); g[3]=bf2f(t1.w);
    bb[0]=bf2f(t2.x); bb[1]=bf2f(t2.y); bb[2]=bf2f(t2.z); bb[3]=bf2f(t2.w);
  } else {
    float4 t1 = ((const float4*)gp)[tid]; float4 t2 = ((const float4*)bp)[tid];
    g[0]=t1.x; g[1]=t1.y; g[2]=t1.z; g[3]=t1.w;
    bb[0]=t2.x; bb[1]=t2.y; bb[2]=t2.z; bb[3]=t2.w;
  }
  ushort4 o;
  o.x = f2bf((v[0]-mean)*rstd*g[0] + bb[0]);
  o.y = f2bf((v[1]-mean)*rstd*g[1] + bb[1]);
  o.z = f2bf((v[2]-mean)*rstd*g[2] + bb[2]);
  o.w = f2bf((v[3]-mean)*rstd*g[3] + bb[3]);
  ((ushort4*)(xn + (size_t)row*DIM))[tid] = o;
}

// ---------- media fp32/bf16 -> bf16 ----------
__global__ __launch_bounds__(256) void cvt_kernel(const void* __restrict__ in, u16* __restrict__ out,
                           const int* __restrict__ flags){
  const int bf = flags[0];
  size_t i = (size_t)blockIdx.x*256 + threadIdx.x;
  if (bf){
    ((ushort4*)out)[i] = ((const ushort4*)in)[i];
  } else {
    float4 t = ((const float4*)in)[i];
    ushort4 o; o.x = f2bf(t.x); o.y = f2bf(t.y); o.z = f2bf(t.z); o.w = f2bf(t.w);
    ((ushort4*)out)[i] = o;
  }
}

// ---------- cumsum of media_locations -> sel ----------
__global__ __launch_bounds__(256) void cumsum_kernel(const void* __restrict__ locp, int* __restrict__ sel,
                              const int* __restrict__ flags){
  const int as32 = flags[1];
  int b = blockIdx.x, tid = threadIdx.x;
  int lane = tid & 63, wid = tid >> 6;
  __shared__ int wsum[4]; __shared__ int carry;
  if (tid == 0) carry = 0;
  __syncthreads();
  for (int t = 0; t < 16; ++t){
    int idx = t*256 + tid;
    int v;
    if (as32) v = (((const int*)locp)[b*SEQN + idx] != 0);
    else      v = (((const uch*)locp)[b*SEQN + idx] != 0);
    int s = v;
    #pragma unroll
    for (int o = 1; o < 64; o <<= 1){ int n = __shfl_up(s, o); if (lane >= o) s += n; }
    if (lane == 63) wsum[wid] = s;
    __syncthreads();
    int wo = carry;
    for (int w = 0; w < wid; ++w) wo += wsum[w];
    int tt = wo + s;
    sel[b*SEQN + idx] = (tt >= 1 && tt <= TT) ? (tt - 1) : -1;
    __syncthreads();
    if (tid == 0) carry += wsum[0] + wsum[1] + wsum[2] + wsum[3];
    __syncthreads();
  }
}

// ---------- zero helpers ----------
__global__ void zero_kernel(float* __restrict__ p, int n){
  int i = blockIdx.x*256 + threadIdx.x;
  if (i < n) p[i] = 0.f;
}
__global__ void zero_small_kernel(int* __restrict__ cnt, int* __restrict__ curs){
  int tid = threadIdx.x;
  if (tid < 68){ cnt[tid] = 0; curs[tid] = 0; }
}

// ---------- bucketing ----------
__global__ __launch_bounds__(256) void count_kernel(const int* __restrict__ sel, int* __restrict__ cnt){
  int t = blockIdx.x*256 + threadIdx.x;
  int b = t >> 12;
  atomicAdd(&cnt[b*17 + sel[t] + 1], 1);
}
__global__ void plan_kernel(const int* __restrict__ cnt, int* __restrict__ offs,
                            int4* __restrict__ desc, int* __restrict__ nblk){
  if (threadIdx.x != 0) return;
  int n = 0;
  for (int b = 0; b < BATCH; ++b){
    int off = 0;
    for (int g = 0; g < 17; ++g){
      int c = cnt[b*17 + g];
      offs[b*17 + g] = off;
      int s = g - 1;
      for (int k = 0; k*64 < c; ++k){
        int4 d; d.x = b; d.y = s; d.z = b*4096 + off + k*64;
        d.w = min(64, c - k*64);
        desc[n++] = d;
      }
      off += c;
    }
  }
  *nblk = n;
}
__global__ __launch_bounds__(256) void scatter_kernel(const int* __restrict__ sel, const int* __restrict__ offs,
                               int* __restrict__ curs, int* __restrict__ tokl){
  int t = blockIdx.x*256 + threadIdx.x;
  int b = t >> 12;
  int g = sel[t] + 1;
  int pos = offs[b*17 + g] + atomicAdd(&curs[b*17 + g], 1);
  tokl[b*4096 + pos] = t;
}

// ---------- V column sums (uniform-softmax fallback) ----------
__global__ __launch_bounds__(512) void vsum_kernel(const u16* __restrict__ kv, float* __restrict__ vsum){
  int b = blockIdx.x, ch = blockIdx.y, c = threadIdx.x;
  size_t base = ((size_t)b*KVN + ch*128)*1024 + 512 + c;
  float s = 0.f;
  for (int r = 0; r < 128; ++r) s += bf2f(kv[base + (size_t)r*1024]);
  atomicAdd(&vsum[b*512 + c], s);
}

// ---------- GEMM: C[M,N] = alpha * A[M,K] @ Bt[N,K]^T ----------
// MODE 0: C bf16.  MODE 1: C bf16 if flags[0] else fp32.  MODE 2: C bf16 + dual-write V^T.
template<int MODE>
__global__ __launch_bounds__(256) void gemm_bt(const u16* __restrict__ A, const u16* __restrict__ Bt,
                        void* __restrict__ Cp, int M, int N, int K, float alpha,
                        const int* __restrict__ flags, u16* __restrict__ vtp){
  __shared__ u16 As[128*64];
  __shared__ u16 Bs[128*64];
  const int tid = threadIdx.x, wid = tid >> 6, lane = tid & 63;
  const int rm = blockIdx.x, rn = blockIdx.y;
  const int wr = wid >> 1, wc = wid & 1;
  const int lr = lane & 15, lg = lane >> 4;
  f32x4 acc[4][4] = {};
  const u16* Ab = A + (size_t)rm*128*K;
  const u16* Bb = Bt + (size_t)rn*128*K;
  for (int k0 = 0; k0 < K; k0 += 64){
    __syncthreads();
    #pragma unroll
    for (int t = 0; t < 4; ++t){
      int c = t*256 + tid;
      int row = c >> 3;
      int qs = (c & 7) ^ (row & 7);
      int ldsOff = (t*256 + wid*64) * 16;
      async16(Ab + (size_t)row*K + k0 + qs*8, (char*)As + ldsOff);
      async16(Bb + (size_t)row*K + k0 + qs*8, (char*)Bs + ldsOff);
    }
    __syncthreads();
    #pragma unroll
    for (int ks = 0; ks < 2; ++ks){
      bf16x8 af[4], bfr[4];
      #pragma unroll
      for (int m = 0; m < 4; ++m){
        int row = wr*64 + m*16 + lr;
        int q = (ks*4 + lg) ^ (row & 7);
        af[m] = *(const bf16x8*)((const char*)As + row*128 + (q << 4));
      }
      #pragma unroll
      for (int n = 0; n < 4; ++n){
        int row = wc*64 + n*16 + lr;
        int q = (ks*4 + lg) ^ (row & 7);
        bfr[n] = *(const bf16x8*)((const char*)Bs + row*128 + (q << 4));
      }
      #pragma unroll
      for (int m = 0; m < 4; ++m)
        #pragma unroll
        for (int n = 0; n < 4; ++n)
          acc[m][n] = __builtin_amdgcn_mfma_f32_16x16x32_bf16(af[m], bfr[n], acc[m][n], 0, 0, 0);
    }
  }
  const bool obf = (MODE != 1) || (flags[0] != 0);
  #pragma unroll
  for (int m = 0; m < 4; ++m){
    #pragma unroll
    for (int n = 0; n < 4; ++n){
      int row0 = rm*128 + wr*64 + m*16 + lg*4;
      int col  = rn*128 + wc*64 + n*16 + lr;
      #pragma unroll
      for (int r = 0; r < 4; ++r){
        float v = acc[m][n][r] * alpha;
        size_t idx = (size_t)(row0 + r)*N + col;
        u16 bv = f2bf(v);
        if (obf) ((u16*)Cp)[idx] = bv;
        else     ((float*)Cp)[idx] = v;
        if (MODE == 2 && col >= 512){
          int row = row0 + r;
          int b = row >> 10, kvi = row & 1023;
          int s = kvi >> 6, rr = kvi & 63;
          vtp[((size_t)((b*16 + s)*512 + (col - 512)))*64 + rr] = bv;
        }
      }
    }
  }
}

// ---------- grouped masked attention ----------
// One block = one chunk of <=64 tokens sharing (b, sel). 4 waves x 16 tokens.
// Per head: stage K_h [64kv][64dh] and Vt_h [64dh][64kv] in swizzled LDS,
// S = Q Kh^T (MFMA), wave softmax, P via LDS redistribution, O = P Vt (MFMA).
__global__ __launch_bounds__(256) void attn2_kernel(
    const u16* __restrict__ qb, const u16* __restrict__ kvb, const u16* __restrict__ vt,
    const int* __restrict__ tokl, const int* __restrict__ nblk, const int4* __restrict__ desc,
    const float* __restrict__ vsum, u16* __restrict__ aout){
  __shared__ u16 Ks[64*64];
  __shared__ u16 Vs[64*64];
  __shared__ u16 Ps[4][16*72];     // pad to 72 (144B rows, 16B-aligned)
  __shared__ int toks[64];
  if (blockIdx.x >= *nblk) return;
  const int4 d = desc[blockIdx.x];
  const int b = d.x, s = d.y, base = d.z, cnt = d.w;
  const int tid = threadIdx.x, w = tid >> 6, lane = tid & 63;
  if (tid < 64) toks[tid] = tokl[base + (tid < cnt ? tid : 0)];
  __syncthreads();
  if (s < 0){
    // uniform softmax over all KV -> mean of V
    const float inv = 1.f/1024.f;
    for (int idx = tid; idx < cnt*512; idx += 256){
      int slot = idx >> 9, c = idx & 511;
      aout[(size_t)toks[slot]*512 + c] = f2bf(vsum[b*512 + c]*inv);
    }
    return;
  }
  const int lr = lane & 15, lg = lane >> 4;
  const size_t kbase = ((size_t)(b*1024 + s*64))*1024;
  const size_t vbase = ((size_t)(b*16 + s))*512*64;
  const int myslot = w*16 + lr;
  const size_t qrow = (size_t)toks[myslot]*512;
  for (int h = 0; h < HEADS; ++h){
    __syncthreads();                       // prior compute done reading Ks/Vs
    #pragma unroll
    for (int t = 0; t < 2; ++t){
      int ci = t*256 + tid;                // 0..511
      int r = ci >> 3, q = ci & 7;
      int qs = (q ^ (r & 7)) << 3;
      async16(kvb + kbase + (size_t)r*1024 + h*64 + qs, (char*)Ks + ci*16);
      async16(vt + vbase + (size_t)(h*64 + r)*64 + qs, (char*)Vs + ci*16);
    }
    __syncthreads();
    // Q fragments (A-operand: row = lane&15 = token slot, k = lg*8)
    bf16x8 qa0 = *(const bf16x8*)(qb + qrow + h*64 + lg*8);
    bf16x8 qa1 = *(const bf16x8*)(qb + qrow + h*64 + 32 + lg*8);
    // S = Q Kh^T
    f32x4 sv[4] = {};
    #pragma unroll
    for (int n = 0; n < 4; ++n){
      int row = n*16 + lr;
      int sl0 = (lg) ^ (row & 7);
      int sl1 = (4 + lg) ^ (row & 7);
      bf16x8 kb0 = *(const bf16x8*)((const char*)Ks + row*128 + sl0*16);
      sv[n] = __builtin_amdgcn_mfma_f32_16x16x32_bf16(qa0, kb0, sv[n], 0, 0, 0);
      bf16x8 kb1 = *(const bf16x8*)((const char*)Ks + row*128 + sl1*16);
      sv[n] = __builtin_amdgcn_mfma_f32_16x16x32_bf16(qa1, kb1, sv[n], 0, 0, 0);
    }
    // row softmax: rows 4*lg+r, spread over 16-lane group + 4 register tiles
    float inv[4];
    #pragma unroll
    for (int r = 0; r < 4; ++r){
      float m = fmaxf(fmaxf(sv[0][r], sv[1][r]), fmaxf(sv[2][r], sv[3][r]));
      #pragma unroll
      for (int o = 1; o < 16; o <<= 1) m = fmaxf(m, __shfl_xor(m, o));
      float s0 = 0.f;
      #pragma unroll
      for (int n = 0; n < 4; ++n){ sv[n][r] = __expf(sv[n][r] - m); s0 += sv[n][r]; }
      #pragma unroll
      for (int o = 1; o < 16; o <<= 1) s0 += __shfl_xor(s0, o);
      inv[r] = 1.f / s0;
    }
    // P -> LDS (wave-private) in [16 tok][72] layout
    u16* pw = &Ps[w][0];
    #pragma unroll
    for (int n = 0; n < 4; ++n)
      #pragma unroll
      for (int r = 0; r < 4; ++r)
        pw[(4*lg + r)*72 + n*16 + lr] = f2bf(sv[n][r] * inv[r]);
    // P A-fragments: row = lr, k = ks*32 + lg*8
    bf16x8 pa0 = *(const bf16x8*)((const char*)pw + lr*144 + lg*16);
    bf16x8 pa1 = *(const bf16x8*)((const char*)pw + lr*144 + 64 + lg*16);
    // O = P Vt
    f32x4 ov[4] = {};
    #pragma unroll
    for (int n = 0; n < 4; ++n){
      int row = n*16 + lr;
      int sl0 = (lg) ^ (row & 7);
      int sl1 = (4 + lg) ^ (row & 7);
      bf16x8 vb0 = *(const bf16x8*)((const char*)Vs + row*128 + sl0*16);
      ov[n] = __builtin_amdgcn_mfma_f32_16x16x32_bf16(pa0, vb0, ov[n], 0, 0, 0);
      bf16x8 vb1 = *(const bf16x8*)((const char*)Vs + row*128 + sl1*16);
      ov[n] = __builtin_amdgcn_mfma_f32_16x16x32_bf16(pa1, vb1, ov[n], 0, 0, 0);
    }
    // write O rows (guard padded slots)
    #pragma unroll
    for (int r = 0; r < 4; ++r){
      int slot = w*16 + 4*lg + r;
      if (slot < cnt){
        size_t orow = (size_t)toks[slot]*512 + h*64;
        #pragma unroll
        for (int n = 0; n < 4; ++n)
          aout[orow + n*16 + lr] = f2bf(ov[n][r]);
      }
    }
  }
}

extern "C" void kernel_launch(void* const* d_in, const int* in_sizes, int n_in,
                              void* d_out, int out_size, void* d_ws, size_t ws_size,
                              hipStream_t stream){
  const void* x      = d_in[0];
  const void* media  = d_in[1];
  const void* mloc   = d_in[2];
  const void* ln_g   = d_in[3];
  const void* ln_b   = d_in[4];
  const void* Wq     = d_in[5];
  const void* Wk     = d_in[6];
  const void* Wv     = d_in[7];
  const void* Wo     = d_in[8];
  char* ws = (char*)d_ws;
  u16* xn    = (u16*)(ws + OFF_XN);
  u16* medb  = (u16*)(ws + OFF_MEDIA);
  u16* qb    = (u16*)(ws + OFF_Q);
  u16* kvb   = (u16*)(ws + OFF_KV);
  u16* aout  = (u16*)(ws + OFF_AOUT);
  u16* WqT   = (u16*)(ws + OFF_WQT);
  u16* WkvT  = (u16*)(ws + OFF_WKVT);
  u16* WoT   = (u16*)(ws + OFF_WOT);
  int* sel   = (int*)(ws + OFF_SEL);
  float* vsm = (float*)(ws + OFF_VSUM);
  int* flags = (int*)(ws + OFF_FLAGS);
  u16* vt    = (u16*)(ws + OFF_VT);
  int* tokl  = (int*)(ws + OFF_TOKL);
  int* gcnt  = (int*)(ws + OFF_CNT);
  int* gcurs = (int*)(ws + OFF_CURS);
  int* goffs = (int*)(ws + OFF_OFFS);
  int* nblk  = (int*)(ws + OFF_NBLK);
  int4* desc = (int4*)(ws + OFF_DESC);

  detect_kernel<<<1, 256, 0, stream>>>((const unsigned int*)x, (const uch*)mloc, flags);

  dim3 tb(32, 8);
  wtrans_kernel<<<dim3(16, 32), tb, 0, stream>>>(Wq, WqT, DIM, INNER, flags);
  wtrans_kernel<<<dim3(16, 32), tb, 0, stream>>>(Wk, WkvT, DIM, INNER, flags);
  wtrans_kernel<<<dim3(16, 32), tb, 0, stream>>>(Wv, WkvT + (size_t)512*1024, DIM, INNER, flags);
  wtrans_kernel<<<dim3(32, 16), tb, 0, stream>>>(Wo, WoT, INNER, DIM, flags);

  zero_kernel<<<8, 256, 0, stream>>>(vsm, BATCH*512);
  zero_small_kernel<<<1, 256, 0, stream>>>(gcnt, gcurs);
  ln_kernel<<<NTOK, 256, 0, stream>>>(x, ln_g, ln_b, xn, flags);
  cvt_kernel<<<4096, 256, 0, stream>>>(media, medb, flags);
  cumsum_kernel<<<BATCH, 256, 0, stream>>>(mloc, sel, flags);

  // bucketing
  count_kernel<<<NTOK/256, 256, 0, stream>>>(sel, gcnt);
  plan_kernel<<<1, 64, 0, stream>>>(gcnt, goffs, desc, nblk);
  scatter_kernel<<<NTOK/256, 256, 0, stream>>>(sel, goffs, gcurs, tokl);

  // q = (xn @ Wq) * DH^-0.5
  gemm_bt<0><<<dim3(128, 4), 256, 0, stream>>>(xn, WqT, qb, NTOK, INNER, DIM, 0.125f, flags, nullptr);
  // kv = media @ [Wk | Wv], dual-writing V^T
  gemm_bt<2><<<dim3(32, 8), 256, 0, stream>>>(medb, WkvT, kvb, BATCH*KVN, 1024, DIM, 1.f, flags, vt);

  vsum_kernel<<<dim3(BATCH, 8), 512, 0, stream>>>(kvb, vsm);
  attn2_kernel<<<MAXBLK, 256, 0, stream>>>(qb, kvb, vt, tokl, nblk, desc, vsm, aout);

  // out = aout @ Wo
  gemm_bt<1><<<dim3(128, 8), 256, 0, stream>>>(aout, WoT, d_out, NTOK, DIM, INNER, 1.f, flags, nullptr);
}

// Round 3
// 199.642 us; speedup vs baseline: 1.7175x; 1.7136x over previous
//
#include <hip/hip_runtime.h>

using u16 = unsigned short;
using uch = unsigned char;

typedef __bf16 bf16x8 __attribute__((ext_vector_type(8)));
typedef float f32x4 __attribute__((ext_vector_type(4)));

// ---------- constants ----------
#define BATCH 4
#define SEQN 4096
#define TT 16
#define MM 64
#define DIM 1024
#define HEADS 8
#define DH 64
#define INNER 512
#define KVN 1024
#define NTOK (BATCH*SEQN)          // 16384
#define MAXBLK 352                 // 4 * (64 + 18) upper bound on chunk count

// ws offsets (bytes)
#define OFF_XN     ((size_t)0)                     // 16384x1024 bf16 = 32MB
#define OFF_MEDIA  ((size_t)33554432)              // 4096x1024 bf16 = 8MB
#define OFF_Q      ((size_t)41943040)              // 16384x512 bf16 = 16MB
#define OFF_KV     ((size_t)58720256)              // 4096x1024 bf16 = 8MB
#define OFF_AOUT   ((size_t)67108864)              // 16384x512 bf16 = 16MB
#define OFF_WQT    ((size_t)83886080)              // 512x1024 bf16 = 1MB
#define OFF_WKVT   ((size_t)84934656)              // 1024x1024 bf16 = 2MB
#define OFF_WOT    ((size_t)87031808)              // 1024x512 bf16 = 1MB
#define OFF_TTA    ((size_t)88080384)              // 16384 int = 64KB (text_time)
#define OFF_VSUM   ((size_t)88145920)              // 4x512 f32 = 8KB
#define OFF_FLAGS  ((size_t)88154112)              // int[2]
#define OFF_VT     ((size_t)88155136)              // 64 groups x 512 x 64 bf16 = 4MB
#define OFF_BOUND  ((size_t)92349440)              // 4x18 int
#define OFF_NBLK   ((size_t)92350464)              // int
#define OFF_DESC   ((size_t)92351488)              // MAXBLK x int4 = 5632B

__device__ __forceinline__ u16 f2bf(float f){
  unsigned int u = __float_as_uint(f);
  u += 0x7fffu + ((u >> 16) & 1u);
  return (u16)(u >> 16);
}
__device__ __forceinline__ float bf2f(u16 b){ return __uint_as_float(((unsigned int)b) << 16); }

__device__ __forceinline__ void async16(const u16* g, void* l){
  __builtin_amdgcn_global_load_lds((__attribute__((address_space(1))) void*)(g),
                                   (__attribute__((address_space(3))) void*)(l), 16, 0, 0);
}

// ---------- format detection ----------
__global__ void detect_kernel(const unsigned int* __restrict__ x, const uch* __restrict__ loc,
                              int* __restrict__ flags){
  __shared__ int cnt, nonz;
  int tid = threadIdx.x;
  if (tid == 0){ cnt = 0; nonz = 0; }
  __syncthreads();
  int c = 0;
  for (int t = 0; t < 4; ++t){
    unsigned int w = x[t*256 + tid];
    unsigned int e = (w >> 7) & 0xFFu;
    if (e >= 110u && e <= 140u) c++;
  }
  atomicAdd(&cnt, c);
  int nz = 0;
  for (int t = 0; t < 16; ++t){
    int i = t*256 + tid;
    if ((i & 3) && loc[i]) nz++;
  }
  atomicAdd(&nonz, nz);
  __syncthreads();
  if (tid == 0){ flags[0] = (cnt > 512) ? 1 : 0; flags[1] = (nonz == 0) ? 1 : 0; }
}

// ---------- weight transpose + convert ----------
__global__ void wtrans_kernel(const void* __restrict__ in, u16* __restrict__ out, int K, int N,
                              const int* __restrict__ flags){
  const int bf = flags[0];
  __shared__ float tile[32][33];
  int n0 = blockIdx.x*32, k0 = blockIdx.y*32;
  int tx = threadIdx.x, ty = threadIdx.y;
  #pragma unroll
  for (int i = 0; i < 4; ++i){
    size_t idx = (size_t)(k0 + ty + i*8)*N + n0 + tx;
    tile[ty + i*8][tx] = bf ? bf2f(((const u16*)in)[idx]) : ((const float*)in)[idx];
  }
  __syncthreads();
  #pragma unroll
  for (int i = 0; i < 4; ++i)
    out[(size_t)(n0 + ty + i*8)*K + k0 + tx] = f2bf(tile[tx][ty + i*8]);
}

// ---------- LayerNorm -> bf16 ----------
__global__ __launch_bounds__(256) void ln_kernel(const void* __restrict__ xp, const void* __restrict__ gp,
                          const void* __restrict__ bp, u16* __restrict__ xn, const int* __restrict__ flags){
  const int bf = flags[0];
  const int row = blockIdx.x, tid = threadIdx.x;
  float v[4];
  if (bf){
    ushort4 t = ((const ushort4*)((const u16*)xp + (size_t)row*DIM))[tid];
    v[0]=bf2f(t.x); v[1]=bf2f(t.y); v[2]=bf2f(t.z); v[3]=bf2f(t.w);
  } else {
    float4 t = ((const float4*)((const float*)xp + (size_t)row*DIM))[tid];
    v[0]=t.x; v[1]=t.y; v[2]=t.z; v[3]=t.w;
  }
  float s = v[0]+v[1]+v[2]+v[3];
  float sq = v[0]*v[0]+v[1]*v[1]+v[2]*v[2]+v[3]*v[3];
  #pragma unroll
  for (int o = 32; o > 0; o >>= 1){ s += __shfl_down(s, o); sq += __shfl_down(sq, o); }
  __shared__ float ss[4], ssq[4];
  int wid = tid >> 6, lane = tid & 63;
  if (lane == 0){ ss[wid] = s; ssq[wid] = sq; }
  __syncthreads();
  s = ss[0]+ss[1]+ss[2]+ss[3]; sq = ssq[0]+ssq[1]+ssq[2]+ssq[3];
  float mean = s * (1.f/DIM);
  float rstd = rsqrtf(sq * (1.f/DIM) - mean*mean + 1e-5f);
  float g[4], bb[4];
  if (bf){
    ushort4 t1 = ((const ushort4*)gp)[tid]; ushort4 t2 = ((const ushort4*)bp)[tid];
    g[0]=bf2f(t1.x); g[1]=bf2f(t1.y); g[2]=bf2f(t1.z); g[3]=bf2f(t1.w);
    bb[0]=bf2f(t2.x); bb[1]=bf2f(t2.y); bb[2]=bf2f(t2.z); bb[3]=bf2f(t2.w);
  } else {
    float4 t1 = ((const float4*)gp)[tid]; float4 t2 = ((const float4*)bp)[tid];
    g[0]=t1.x; g[1]=t1.y; g[2]=t1.z; g[3]=t1.w;
    bb[0]=t2.x; bb[1]=t2.y; bb[2]=t2.z; bb[3]=t2.w;
  }
  ushort4 o;
  o.x = f2bf((v[0]-mean)*rstd*g[0] + bb[0]);
  o.y = f2bf((v[1]-mean)*rstd*g[1] + bb[1]);
  o.z = f2bf((v[2]-mean)*rstd*g[2] + bb[2]);
  o.w = f2bf((v[3]-mean)*rstd*g[3] + bb[3]);
  ((ushort4*)(xn + (size_t)row*DIM))[tid] = o;
}

// ---------- media fp32/bf16 -> bf16 ----------
__global__ __launch_bounds__(256) void cvt_kernel(const void* __restrict__ in, u16* __restrict__ out,
                           const int* __restrict__ flags){
  const int bf = flags[0];
  size_t i = (size_t)blockIdx.x*256 + threadIdx.x;
  if (bf){
    ((ushort4*)out)[i] = ((const ushort4*)in)[i];
  } else {
    float4 t = ((const float4*)in)[i];
    ushort4 o; o.x = f2bf(t.x); o.y = f2bf(t.y); o.z = f2bf(t.z); o.w = f2bf(t.w);
    ((ushort4*)out)[i] = o;
  }
}

// ---------- cumsum of media_locations -> text_time ----------
__global__ __launch_bounds__(256) void cumsum_kernel(const void* __restrict__ locp, int* __restrict__ tta,
                              const int* __restrict__ flags){
  const int as32 = flags[1];
  int b = blockIdx.x, tid = threadIdx.x;
  int lane = tid & 63, wid = tid >> 6;
  __shared__ int wsum[4]; __shared__ int carry;
  if (tid == 0) carry = 0;
  __syncthreads();
  for (int t = 0; t < 16; ++t){
    int idx = t*256 + tid;
    int v;
    if (as32) v = (((const int*)locp)[b*SEQN + idx] != 0);
    else      v = (((const uch*)locp)[b*SEQN + idx] != 0);
    int s = v;
    #pragma unroll
    for (int o = 1; o < 64; o <<= 1){ int n = __shfl_up(s, o); if (lane >= o) s += n; }
    if (lane == 63) wsum[wid] = s;
    __syncthreads();
    int wo = carry;
    for (int w = 0; w < wid; ++w) wo += wsum[w];
    tta[b*SEQN + idx] = wo + s;
    __syncthreads();
    if (tid == 0) carry += wsum[0] + wsum[1] + wsum[2] + wsum[3];
    __syncthreads();
  }
}

// ---------- run boundaries (no atomics: tt is monotone, +0/+1 steps) ----------
__global__ __launch_bounds__(256) void bounds_kernel(const int* __restrict__ tta, int* __restrict__ bound){
  int t = blockIdx.x*256 + threadIdx.x;
  int b = t >> 12, n = t & 4095;
  int cur = tta[t];
  int prev = n ? tta[t-1] : 0;
  if (cur > prev && cur <= 17) bound[b*18 + cur] = n;
}

// ---------- init ----------
__global__ void zero_kernel(float* __restrict__ p, int n){
  int i = blockIdx.x*256 + threadIdx.x;
  if (i < n) p[i] = 0.f;
}
__global__ void init_bound_kernel(int* __restrict__ bound){
  int tid = threadIdx.x;
  if (tid < 72) bound[tid] = 4096;
}

// ---------- plan: contiguous ranges -> chunk descriptors ----------
__global__ void plan_kernel(const int* __restrict__ bound, int4* __restrict__ desc,
                            int* __restrict__ nblk){
  if (threadIdx.x != 0) return;
  int n = 0;
  for (int b = 0; b < BATCH; ++b){
    int bnd[19];
    bnd[0] = 0;
    for (int g = 1; g <= 17; ++g) bnd[g] = bound[b*18 + g];
    bnd[18] = 4096;
    for (int g = 0; g <= 17; ++g){
      int lo = bnd[g];
      int hi = (g < 17) ? bnd[g+1] : 4096;
      if (lo >= 4096) lo = 4096;
      int s = (g == 0 || g == 17) ? -1 : (g - 1);
      for (int k = lo; k < hi; k += 64){
        int4 d; d.x = b; d.y = s; d.z = b*4096 + k; d.w = min(64, hi - k);
        desc[n++] = d;
      }
    }
  }
  *nblk = n;
}

// ---------- V column sums (uniform-softmax fallback) ----------
__global__ __launch_bounds__(512) void vsum_kernel(const u16* __restrict__ kv, float* __restrict__ vsum){
  int b = blockIdx.x, ch = blockIdx.y, c = threadIdx.x;
  size_t base = ((size_t)b*KVN + ch*128)*1024 + 512 + c;
  float s = 0.f;
  for (int r = 0; r < 128; ++r) s += bf2f(kv[base + (size_t)r*1024]);
  atomicAdd(&vsum[b*512 + c], s);
}

// ---------- GEMM: C[M,N] = alpha * A[M,K] @ Bt[N,K]^T ----------
// MODE 0: C bf16.  MODE 1: C bf16 if flags[0] else fp32.  MODE 2: C bf16 + dual-write V^T.
template<int MODE>
__global__ __launch_bounds__(256) void gemm_bt(const u16* __restrict__ A, const u16* __restrict__ Bt,
                        void* __restrict__ Cp, int M, int N, int K, float alpha,
                        const int* __restrict__ flags, u16* __restrict__ vtp){
  __shared__ u16 As[128*64];
  __shared__ u16 Bs[128*64];
  const int tid = threadIdx.x, wid = tid >> 6, lane = tid & 63;
  const int rm = blockIdx.x, rn = blockIdx.y;
  const int wr = wid >> 1, wc = wid & 1;
  const int lr = lane & 15, lg = lane >> 4;
  f32x4 acc[4][4] = {};
  const u16* Ab = A + (size_t)rm*128*K;
  const u16* Bb = Bt + (size_t)rn*128*K;
  for (int k0 = 0; k0 < K; k0 += 64){
    __syncthreads();
    #pragma unroll
    for (int t = 0; t < 4; ++t){
      int c = t*256 + tid;
      int row = c >> 3;
      int qs = (c & 7) ^ (row & 7);
      int ldsOff = (t*256 + wid*64) * 16;
      async16(Ab + (size_t)row*K + k0 + qs*8, (char*)As + ldsOff);
      async16(Bb + (size_t)row*K + k0 + qs*8, (char*)Bs + ldsOff);
    }
    __syncthreads();
    #pragma unroll
    for (int ks = 0; ks < 2; ++ks){
      bf16x8 af[4], bfr[4];
      #pragma unroll
      for (int m = 0; m < 4; ++m){
        int row = wr*64 + m*16 + lr;
        int q = (ks*4 + lg) ^ (row & 7);
        af[m] = *(const bf16x8*)((const char*)As + row*128 + (q << 4));
      }
      #pragma unroll
      for (int n = 0; n < 4; ++n){
        int row = wc*64 + n*16 + lr;
        int q = (ks*4 + lg) ^ (row & 7);
        bfr[n] = *(const bf16x8*)((const char*)Bs + row*128 + (q << 4));
      }
      #pragma unroll
      for (int m = 0; m < 4; ++m)
        #pragma unroll
        for (int n = 0; n < 4; ++n)
          acc[m][n] = __builtin_amdgcn_mfma_f32_16x16x32_bf16(af[m], bfr[n], acc[m][n], 0, 0, 0);
    }
  }
  const bool obf = (MODE != 1) || (flags[0] != 0);
  #pragma unroll
  for (int m = 0; m < 4; ++m){
    #pragma unroll
    for (int n = 0; n < 4; ++n){
      int row0 = rm*128 + wr*64 + m*16 + lg*4;
      int col  = rn*128 + wc*64 + n*16 + lr;
      #pragma unroll
      for (int r = 0; r < 4; ++r){
        float v = acc[m][n][r] * alpha;
        size_t idx = (size_t)(row0 + r)*N + col;
        u16 bv = f2bf(v);
        if (obf) ((u16*)Cp)[idx] = bv;
        else     ((float*)Cp)[idx] = v;
        if (MODE == 2 && col >= 512){
          int row = row0 + r;
          int b = row >> 10, kvi = row & 1023;
          int s = kvi >> 6, rr = kvi & 63;
          vtp[((size_t)((b*16 + s)*512 + (col - 512)))*64 + rr] = bv;
        }
      }
    }
  }
}

// ---------- grouped masked attention (contiguous token runs) ----------
__global__ __launch_bounds__(256) void attn2_kernel(
    const u16* __restrict__ qb, const u16* __restrict__ kvb, const u16* __restrict__ vt,
    const int* __restrict__ nblk, const int4* __restrict__ desc,
    const float* __restrict__ vsum, u16* __restrict__ aout){
  __shared__ u16 Ks[64*64];
  __shared__ u16 Vs[64*64];
  __shared__ u16 Ps[4][16*72];     // pad to 72 (144B rows, 16B-aligned)
  if (blockIdx.x >= *nblk) return;
  const int4 d = desc[blockIdx.x];
  const int b = d.x, s = d.y, rowStart = d.z, cnt = d.w;
  const int tid = threadIdx.x, w = tid >> 6, lane = tid & 63;
  if (s < 0){
    // uniform softmax over all KV -> mean of V; contiguous rows
    const float inv = 1.f/1024.f;
    for (int idx = tid; idx < cnt*512; idx += 256){
      int slot = idx >> 9, c = idx & 511;
      aout[(size_t)(rowStart + slot)*512 + c] = f2bf(vsum[b*512 + c]*inv);
    }
    return;
  }
  const int lr = lane & 15, lg = lane >> 4;
  const size_t kbase = ((size_t)(b*1024 + s*64))*1024;
  const size_t vbase = ((size_t)(b*16 + s))*512*64;
  const int myslot = w*16 + lr;
  const size_t qrow = (size_t)(rowStart + min(myslot, cnt - 1))*512;
  for (int h = 0; h < HEADS; ++h){
    __syncthreads();                       // prior compute done reading Ks/Vs
    #pragma unroll
    for (int t = 0; t < 2; ++t){
      int ci = t*256 + tid;                // 0..511
      int r = ci >> 3, q = ci & 7;
      int qs = (q ^ (r & 7)) << 3;
      async16(kvb + kbase + (size_t)r*1024 + h*64 + qs, (char*)Ks + ci*16);
      async16(vt + vbase + (size_t)(h*64 + r)*64 + qs, (char*)Vs + ci*16);
    }
    __syncthreads();
    // Q fragments (A-operand: row = lane&15 = token slot, k = lg*8)
    bf16x8 qa0 = *(const bf16x8*)(qb + qrow + h*64 + lg*8);
    bf16x8 qa1 = *(const bf16x8*)(qb + qrow + h*64 + 32 + lg*8);
    // S = Q Kh^T
    f32x4 sv[4] = {};
    #pragma unroll
    for (int n = 0; n < 4; ++n){
      int row = n*16 + lr;
      int sl0 = (lg) ^ (row & 7);
      int sl1 = (4 + lg) ^ (row & 7);
      bf16x8 kb0 = *(const bf16x8*)((const char*)Ks + row*128 + sl0*16);
      sv[n] = __builtin_amdgcn_mfma_f32_16x16x32_bf16(qa0, kb0, sv[n], 0, 0, 0);
      bf16x8 kb1 = *(const bf16x8*)((const char*)Ks + row*128 + sl1*16);
      sv[n] = __builtin_amdgcn_mfma_f32_16x16x32_bf16(qa1, kb1, sv[n], 0, 0, 0);
    }
    // row softmax: rows 4*lg+r, spread over 16-lane group + 4 register tiles
    float inv[4];
    #pragma unroll
    for (int r = 0; r < 4; ++r){
      float m = fmaxf(fmaxf(sv[0][r], sv[1][r]), fmaxf(sv[2][r], sv[3][r]));
      #pragma unroll
      for (int o = 1; o < 16; o <<= 1) m = fmaxf(m, __shfl_xor(m, o));
      float s0 = 0.f;
      #pragma unroll
      for (int n = 0; n < 4; ++n){ sv[n][r] = __expf(sv[n][r] - m); s0 += sv[n][r]; }
      #pragma unroll
      for (int o = 1; o < 16; o <<= 1) s0 += __shfl_xor(s0, o);
      inv[r] = 1.f / s0;
    }
    // P -> LDS (wave-private) in [16 tok][72] layout
    u16* pw = &Ps[w][0];
    #pragma unroll
    for (int n = 0; n < 4; ++n)
      #pragma unroll
      for (int r = 0; r < 4; ++r)
        pw[(4*lg + r)*72 + n*16 + lr] = f2bf(sv[n][r] * inv[r]);
    // P A-fragments: row = lr, k = ks*32 + lg*8
    bf16x8 pa0 = *(const bf16x8*)((const char*)pw + lr*144 + lg*16);
    bf16x8 pa1 = *(const bf16x8*)((const char*)pw + lr*144 + 64 + lg*16);
    // O = P Vt
    f32x4 ov[4] = {};
    #pragma unroll
    for (int n = 0; n < 4; ++n){
      int row = n*16 + lr;
      int sl0 = (lg) ^ (row & 7);
      int sl1 = (4 + lg) ^ (row & 7);
      bf16x8 vb0 = *(const bf16x8*)((const char*)Vs + row*128 + sl0*16);
      ov[n] = __builtin_amdgcn_mfma_f32_16x16x32_bf16(pa0, vb0, ov[n], 0, 0, 0);
      bf16x8 vb1 = *(const bf16x8*)((const char*)Vs + row*128 + sl1*16);
      ov[n] = __builtin_amdgcn_mfma_f32_16x16x32_bf16(pa1, vb1, ov[n], 0, 0, 0);
    }
    // write O rows (guard padded slots)
    #pragma unroll
    for (int r = 0; r < 4; ++r){
      int slot = w*16 + 4*lg + r;
      if (slot < cnt){
        size_t orow = (size_t)(rowStart + slot)*512 + h*64;
        #pragma unroll
        for (int n = 0; n < 4; ++n)
          aout[orow + n*16 + lr] = f2bf(ov[n][r]);
      }
    }
  }
}

extern "C" void kernel_launch(void* const* d_in, const int* in_sizes, int n_in,
                              void* d_out, int out_size, void* d_ws, size_t ws_size,
                              hipStream_t stream){
  const void* x      = d_in[0];
  const void* media  = d_in[1];
  const void* mloc   = d_in[2];
  const void* ln_g   = d_in[3];
  const void* ln_b   = d_in[4];
  const void* Wq     = d_in[5];
  const void* Wk     = d_in[6];
  const void* Wv     = d_in[7];
  const void* Wo     = d_in[8];
  char* ws = (char*)d_ws;
  u16* xn    = (u16*)(ws + OFF_XN);
  u16* medb  = (u16*)(ws + OFF_MEDIA);
  u16* qb    = (u16*)(ws + OFF_Q);
  u16* kvb   = (u16*)(ws + OFF_KV);
  u16* aout  = (u16*)(ws + OFF_AOUT);
  u16* WqT   = (u16*)(ws + OFF_WQT);
  u16* WkvT  = (u16*)(ws + OFF_WKVT);
  u16* WoT   = (u16*)(ws + OFF_WOT);
  int* tta   = (int*)(ws + OFF_TTA);
  float* vsm = (float*)(ws + OFF_VSUM);
  int* flags = (int*)(ws + OFF_FLAGS);
  u16* vt    = (u16*)(ws + OFF_VT);
  int* bound = (int*)(ws + OFF_BOUND);
  int* nblk  = (int*)(ws + OFF_NBLK);
  int4* desc = (int4*)(ws + OFF_DESC);

  detect_kernel<<<1, 256, 0, stream>>>((const unsigned int*)x, (const uch*)mloc, flags);

  dim3 tb(32, 8);
  wtrans_kernel<<<dim3(16, 32), tb, 0, stream>>>(Wq, WqT, DIM, INNER, flags);
  wtrans_kernel<<<dim3(16, 32), tb, 0, stream>>>(Wk, WkvT, DIM, INNER, flags);
  wtrans_kernel<<<dim3(16, 32), tb, 0, stream>>>(Wv, WkvT + (size_t)512*1024, DIM, INNER, flags);
  wtrans_kernel<<<dim3(32, 16), tb, 0, stream>>>(Wo, WoT, INNER, DIM, flags);

  zero_kernel<<<8, 256, 0, stream>>>(vsm, BATCH*512);
  init_bound_kernel<<<1, 128, 0, stream>>>(bound);
  ln_kernel<<<NTOK, 256, 0, stream>>>(x, ln_g, ln_b, xn, flags);
  cvt_kernel<<<4096, 256, 0, stream>>>(media, medb, flags);
  cumsum_kernel<<<BATCH, 256, 0, stream>>>(mloc, tta, flags);

  // bucketing: contiguous runs -> boundaries -> descriptors (no atomics)
  bounds_kernel<<<NTOK/256, 256, 0, stream>>>(tta, bound);
  plan_kernel<<<1, 64, 0, stream>>>(bound, desc, nblk);

  // q = (xn @ Wq) * DH^-0.5
  gemm_bt<0><<<dim3(128, 4), 256, 0, stream>>>(xn, WqT, qb, NTOK, INNER, DIM, 0.125f, flags, nullptr);
  // kv = media @ [Wk | Wv], dual-writing V^T
  gemm_bt<2><<<dim3(32, 8), 256, 0, stream>>>(medb, WkvT, kvb, BATCH*KVN, 1024, DIM, 1.f, flags, vt);

  vsum_kernel<<<dim3(BATCH, 8), 512, 0, stream>>>(kvb, vsm);
  attn2_kernel<<<MAXBLK, 256, 0, stream>>>(qb, kvb, vt, nblk, desc, vsm, aout);

  // out = aout @ Wo
  gemm_bt<1><<<dim3(128, 8), 256, 0, stream>>>(aout, WoT, d_out, NTOK, DIM, INNER, 1.f, flags, nullptr);
}

// Round 5
// 180.212 us; speedup vs baseline: 1.9027x; 1.1078x over previous
//
#include <hip/hip_runtime.h>

using u16 = unsigned short;
using uch = unsigned char;

typedef __bf16 bf16x8 __attribute__((ext_vector_type(8)));
typedef float f32x4 __attribute__((ext_vector_type(4)));

// ---------- constants ----------
#define BATCH 4
#define SEQN 4096
#define TT 16
#define MM 64
#define DIM 1024
#define HEADS 8
#define DH 64
#define INNER 512
#define KVN 1024
#define NTOK (BATCH*SEQN)          // 16384
#define MAXBLK 352                 // 4 * (64 + 18) upper bound on chunk count

// ws offsets (bytes)
#define OFF_XN     ((size_t)0)                     // 16384x1024 bf16 = 32MB
#define OFF_MEDIA  ((size_t)33554432)              // 4096x1024 bf16 = 8MB
#define OFF_Q      ((size_t)41943040)              // 16384x512 bf16 = 16MB
#define OFF_KV     ((size_t)58720256)              // 4096x1024 bf16 = 8MB
#define OFF_AOUT   ((size_t)67108864)              // 16384x512 bf16 = 16MB
#define OFF_WQT    ((size_t)83886080)              // 512x1024 bf16 = 1MB
#define OFF_WKVT   ((size_t)84934656)              // 1024x1024 bf16 = 2MB
#define OFF_WOT    ((size_t)87031808)              // 1024x512 bf16 = 1MB
#define OFF_VSUM   ((size_t)88145920)              // 4x512 f32 = 8KB
#define OFF_FLAGS  ((size_t)88154112)              // int[2]
#define OFF_VT     ((size_t)88155136)              // 64 groups x 512 x 64 bf16 = 4MB
#define OFF_BOUND  ((size_t)92349440)              // 4x18 int
#define OFF_NBLK   ((size_t)92350464)              // int
#define OFF_DESC   ((size_t)92351488)              // MAXBLK x int4 = 5632B

__device__ __forceinline__ u16 f2bf(float f){
  unsigned int u = __float_as_uint(f);
  u += 0x7fffu + ((u >> 16) & 1u);
  return (u16)(u >> 16);
}
__device__ __forceinline__ float bf2f(u16 b){ return __uint_as_float(((unsigned int)b) << 16); }

__device__ __forceinline__ void async16(const u16* g, void* l){
  __builtin_amdgcn_global_load_lds((__attribute__((address_space(1))) void*)(g),
                                   (__attribute__((address_space(3))) void*)(l), 16, 0, 0);
}

// ---------- setup: format detect + zero vsum + init bounds (one dispatch) ----------
__global__ void setup_kernel(const unsigned int* __restrict__ x, const uch* __restrict__ loc,
                             int* __restrict__ flags, float* __restrict__ vsum,
                             int* __restrict__ bound){
  __shared__ int cnt, nonz;
  int tid = threadIdx.x;
  if (tid == 0){ cnt = 0; nonz = 0; }
  __syncthreads();
  int c = 0;
  for (int t = 0; t < 4; ++t){
    unsigned int w = x[t*256 + tid];
    unsigned int e = (w >> 7) & 0xFFu;
    if (e >= 110u && e <= 140u) c++;
  }
  atomicAdd(&cnt, c);
  int nz = 0;
  for (int t = 0; t < 16; ++t){
    int i = t*256 + tid;
    if ((i & 3) && loc[i]) nz++;
  }
  atomicAdd(&nonz, nz);
  #pragma unroll
  for (int t = 0; t < 8; ++t) vsum[t*256 + tid] = 0.f;
  if (tid < 72) bound[tid] = 4096;
  __syncthreads();
  if (tid == 0){ flags[0] = (cnt > 512) ? 1 : 0; flags[1] = (nonz == 0) ? 1 : 0; }
}

// ---------- all 4 weight transposes in one dispatch ----------
// flat grid 2048: [0,512) Wq; [512,1024) Wk; [1024,1536) Wv; [1536,2048) Wo
__global__ void wtrans_all_kernel(const void* __restrict__ Wq, const void* __restrict__ Wk,
                                  const void* __restrict__ Wv, const void* __restrict__ Wo,
                                  u16* __restrict__ WqT, u16* __restrict__ WkvT, u16* __restrict__ WoT,
                                  const int* __restrict__ flags){
  const int bf = flags[0];
  __shared__ float tile[32][33];
  int id = blockIdx.x;
  const void* in; u16* out; int K, N, bx, by;
  if (id < 512){       in = Wq; out = WqT;  K = DIM;   N = INNER; int l = id;        bx = l & 15; by = l >> 4; }
  else if (id < 1024){ in = Wk; out = WkvT; K = DIM;   N = INNER; int l = id - 512;  bx = l & 15; by = l >> 4; }
  else if (id < 1536){ in = Wv; out = WkvT + (size_t)512*1024; K = DIM; N = INNER; int l = id - 1024; bx = l & 15; by = l >> 4; }
  else {               in = Wo; out = WoT;  K = INNER; N = DIM;   int l = id - 1536; bx = l & 31; by = l >> 5; }
  int n0 = bx*32, k0 = by*32;
  int tx = threadIdx.x, ty = threadIdx.y;
  #pragma unroll
  for (int i = 0; i < 4; ++i){
    size_t idx = (size_t)(k0 + ty + i*8)*N + n0 + tx;
    tile[ty + i*8][tx] = bf ? bf2f(((const u16*)in)[idx]) : ((const float*)in)[idx];
  }
  __syncthreads();
  #pragma unroll
  for (int i = 0; i < 4; ++i)
    out[(size_t)(n0 + ty + i*8)*K + k0 + tx] = f2bf(tile[tx][ty + i*8]);
}

// ---------- LayerNorm -> bf16 ----------
__global__ __launch_bounds__(256) void ln_kernel(const void* __restrict__ xp, const void* __restrict__ gp,
                          const void* __restrict__ bp, u16* __restrict__ xn, const int* __restrict__ flags){
  const int bf = flags[0];
  const int row = blockIdx.x, tid = threadIdx.x;
  float v[4];
  if (bf){
    ushort4 t = ((const ushort4*)((const u16*)xp + (size_t)row*DIM))[tid];
    v[0]=bf2f(t.x); v[1]=bf2f(t.y); v[2]=bf2f(t.z); v[3]=bf2f(t.w);
  } else {
    float4 t = ((const float4*)((const float*)xp + (size_t)row*DIM))[tid];
    v[0]=t.x; v[1]=t.y; v[2]=t.z; v[3]=t.w;
  }
  float s = v[0]+v[1]+v[2]+v[3];
  float sq = v[0]*v[0]+v[1]*v[1]+v[2]*v[2]+v[3]*v[3];
  #pragma unroll
  for (int o = 32; o > 0; o >>= 1){ s += __shfl_down(s, o); sq += __shfl_down(sq, o); }
  __shared__ float ss[4], ssq[4];
  int wid = tid >> 6, lane = tid & 63;
  if (lane == 0){ ss[wid] = s; ssq[wid] = sq; }
  __syncthreads();
  s = ss[0]+ss[1]+ss[2]+ss[3]; sq = ssq[0]+ssq[1]+ssq[2]+ssq[3];
  float mean = s * (1.f/DIM);
  float rstd = rsqrtf(sq * (1.f/DIM) - mean*mean + 1e-5f);
  float g[4], bb[4];
  if (bf){
    ushort4 t1 = ((const ushort4*)gp)[tid]; ushort4 t2 = ((const ushort4*)bp)[tid];
    g[0]=bf2f(t1.x); g[1]=bf2f(t1.y); g[2]=bf2f(t1.z); g[3]=bf2f(t1.w);
    bb[0]=bf2f(t2.x); bb[1]=bf2f(t2.y); bb[2]=bf2f(t2.z); bb[3]=bf2f(t2.w);
  } else {
    float4 t1 = ((const float4*)gp)[tid]; float4 t2 = ((const float4*)bp)[tid];
    g[0]=t1.x; g[1]=t1.y; g[2]=t1.z; g[3]=t1.w;
    bb[0]=t2.x; bb[1]=t2.y; bb[2]=t2.z; bb[3]=t2.w;
  }
  ushort4 o;
  o.x = f2bf((v[0]-mean)*rstd*g[0] + bb[0]);
  o.y = f2bf((v[1]-mean)*rstd*g[1] + bb[1]);
  o.z = f2bf((v[2]-mean)*rstd*g[2] + bb[2]);
  o.w = f2bf((v[3]-mean)*rstd*g[3] + bb[3]);
  ((ushort4*)(xn + (size_t)row*DIM))[tid] = o;
}

// ---------- media fp32/bf16 -> bf16 ----------
__global__ __launch_bounds__(256) void cvt_kernel(const void* __restrict__ in, u16* __restrict__ out,
                           const int* __restrict__ flags){
  const int bf = flags[0];
  size_t i = (size_t)blockIdx.x*256 + threadIdx.x;
  if (bf){
    ((ushort4*)out)[i] = ((const ushort4*)in)[i];
  } else {
    float4 t = ((const float4*)in)[i];
    ushort4 o; o.x = f2bf(t.x); o.y = f2bf(t.y); o.z = f2bf(t.z); o.w = f2bf(t.w);
    ((ushort4*)out)[i] = o;
  }
}

// ---------- cumsum + boundary detection fused (no tta round-trip) ----------
__global__ __launch_bounds__(256) void cumsum_kernel(const void* __restrict__ locp, int* __restrict__ bound,
                              const int* __restrict__ flags){
  const int as32 = flags[1];
  int b = blockIdx.x, tid = threadIdx.x;
  int lane = tid & 63, wid = tid >> 6;
  __shared__ int wsum[4]; __shared__ int carry;
  if (tid == 0) carry = 0;
  __syncthreads();
  for (int t = 0; t < 16; ++t){
    int idx = t*256 + tid;
    int v;
    if (as32) v = (((const int*)locp)[b*SEQN + idx] != 0);
    else      v = (((const uch*)locp)[b*SEQN + idx] != 0);
    int s = v;
    #pragma unroll
    for (int o = 1; o < 64; o <<= 1){ int n = __shfl_up(s, o); if (lane >= o) s += n; }
    if (lane == 63) wsum[wid] = s;
    __syncthreads();
    int wo = carry;
    for (int w = 0; w < wid; ++w) wo += wsum[w];
    int tt = wo + s;
    // v==1 means tt just incremented -> idx is the FIRST token with this tt
    if (v && tt <= 17) bound[b*18 + tt] = idx;
    __syncthreads();
    if (tid == 0) carry += wsum[0] + wsum[1] + wsum[2] + wsum[3];
    __syncthreads();
  }
}

// ---------- plan: contiguous ranges -> chunk descriptors ----------
__global__ void plan_kernel(const int* __restrict__ bound, int4* __restrict__ desc,
                            int* __restrict__ nblk){
  if (threadIdx.x != 0) return;
  int n = 0;
  for (int b = 0; b < BATCH; ++b){
    int bnd[19];
    bnd[0] = 0;
    for (int g = 1; g <= 17; ++g) bnd[g] = bound[b*18 + g];
    bnd[18] = 4096;
    for (int g = 0; g <= 17; ++g){
      int lo = bnd[g];
      int hi = (g < 17) ? bnd[g+1] : 4096;
      if (lo >= 4096) lo = 4096;
      int s = (g == 0 || g == 17) ? -1 : (g - 1);
      for (int k = lo; k < hi; k += 64){
        int4 d; d.x = b; d.y = s; d.z = b*4096 + k; d.w = min(64, hi - k);
        desc[n++] = d;
      }
    }
  }
  *nblk = n;
}

// ---------- V column sums (uniform-softmax fallback) ----------
__global__ __launch_bounds__(512) void vsum_kernel(const u16* __restrict__ kv, float* __restrict__ vsum){
  int b = blockIdx.x, ch = blockIdx.y, c = threadIdx.x;
  size_t base = ((size_t)b*KVN + ch*128)*1024 + 512 + c;
  float s = 0.f;
  for (int r = 0; r < 128; ++r) s += bf2f(kv[base + (size_t)r*1024]);
  atomicAdd(&vsum[b*512 + c], s);
}

// ---------- GEMM: C[M,N] = alpha * A[M,K] @ Bt[N,K]^T ----------
// Launch with grid (N/128, M/128): x = rn (fast), y = rm. XCD-chunk swizzled.
// MODE 0: C bf16.  MODE 1: C bf16 if flags[0] else fp32.  MODE 2: C bf16 + dual-write V^T.
template<int MODE>
__global__ __launch_bounds__(256) void gemm_bt(const u16* __restrict__ A, const u16* __restrict__ Bt,
                        void* __restrict__ Cp, int M, int N, int K, float alpha,
                        const int* __restrict__ flags, u16* __restrict__ vtp){
  __shared__ u16 As[128*64];
  __shared__ u16 Bs[128*64];
  const int tid = threadIdx.x, wid = tid >> 6, lane = tid & 63;
  // XCD-aware bijective swizzle (nwg % 8 == 0 for all our grids): each XCD
  // gets a contiguous chunk of rn-fast flat ids -> A row-tiles reused in-L2.
  int flat = blockIdx.x + blockIdx.y*gridDim.x;
  int cpx = (gridDim.x*gridDim.y) >> 3;
  int wg = (flat & 7)*cpx + (flat >> 3);
  const int rn = wg % gridDim.x, rm = wg / gridDim.x;
  const int wr = wid >> 1, wc = wid & 1;
  const int lr = lane & 15, lg = lane >> 4;
  f32x4 acc[4][4] = {};
  const u16* Ab = A + (size_t)rm*128*K;
  const u16* Bb = Bt + (size_t)rn*128*K;
  for (int k0 = 0; k0 < K; k0 += 64){
    __syncthreads();
    #pragma unroll
    for (int t = 0; t < 4; ++t){
      int c = t*256 + tid;
      int row = c >> 3;
      int qs = (c & 7) ^ (row & 7);
      int ldsOff = (t*256 + wid*64) * 16;
      async16(Ab + (size_t)row*K + k0 + qs*8, (char*)As + ldsOff);
      async16(Bb + (size_t)row*K + k0 + qs*8, (char*)Bs + ldsOff);
    }
    __syncthreads();
    #pragma unroll
    for (int ks = 0; ks < 2; ++ks){
      bf16x8 af[4], bfr[4];
      #pragma unroll
      for (int m = 0; m < 4; ++m){
        int row = wr*64 + m*16 + lr;
        int q = (ks*4 + lg) ^ (row & 7);
        af[m] = *(const bf16x8*)((const char*)As + row*128 + (q << 4));
      }
      #pragma unroll
      for (int n = 0; n < 4; ++n){
        int row = wc*64 + n*16 + lr;
        int q = (ks*4 + lg) ^ (row & 7);
        bfr[n] = *(const bf16x8*)((const char*)Bs + row*128 + (q << 4));
      }
      #pragma unroll
      for (int m = 0; m < 4; ++m)
        #pragma unroll
        for (int n = 0; n < 4; ++n)
          acc[m][n] = __builtin_amdgcn_mfma_f32_16x16x32_bf16(af[m], bfr[n], acc[m][n], 0, 0, 0);
    }
  }
  const bool obf = (MODE != 1) || (flags[0] != 0);
  #pragma unroll
  for (int m = 0; m < 4; ++m){
    #pragma unroll
    for (int n = 0; n < 4; ++n){
      int row0 = rm*128 + wr*64 + m*16 + lg*4;
      int col  = rn*128 + wc*64 + n*16 + lr;
      #pragma unroll
      for (int r = 0; r < 4; ++r){
        float v = acc[m][n][r] * alpha;
        size_t idx = (size_t)(row0 + r)*N + col;
        u16 bv = f2bf(v);
        if (obf) ((u16*)Cp)[idx] = bv;
        else     ((float*)Cp)[idx] = v;
        if (MODE == 2 && col >= 512){
          int row = row0 + r;
          int b = row >> 10, kvi = row & 1023;
          int s = kvi >> 6, rr = kvi & 63;
          vtp[((size_t)((b*16 + s)*512 + (col - 512)))*64 + rr] = bv;
        }
      }
    }
  }
}

// ---------- grouped masked attention (contiguous token runs, head-split) ----------
// grid (MAXBLK, 4): blockIdx.y = head-group of 2 heads.
__global__ __launch_bounds__(256) void attn2_kernel(
    const u16* __restrict__ qb, const u16* __restrict__ kvb, const u16* __restrict__ vt,
    const int* __restrict__ nblk, const int4* __restrict__ desc,
    const float* __restrict__ vsum, u16* __restrict__ aout){
  __shared__ u16 Ks[64*64];
  __shared__ u16 Vs[64*64];
  __shared__ u16 Ps[4][16*72];     // pad to 72 (144B rows, 16B-aligned)
  if (blockIdx.x >= *nblk) return;
  const int4 d = desc[blockIdx.x];
  const int b = d.x, s = d.y, rowStart = d.z, cnt = d.w;
  const int hg = blockIdx.y;       // heads hg*2, hg*2+1
  const int tid = threadIdx.x, w = tid >> 6, lane = tid & 63;
  if (s < 0){
    // uniform softmax over all KV -> mean of V; this block owns cols [hg*128, hg*128+128)
    const float inv = 1.f/1024.f;
    for (int idx = tid; idx < cnt*128; idx += 256){
      int slot = idx >> 7, c = hg*128 + (idx & 127);
      aout[(size_t)(rowStart + slot)*512 + c] = f2bf(vsum[b*512 + c]*inv);
    }
    return;
  }
  const int lr = lane & 15, lg = lane >> 4;
  const size_t kbase = ((size_t)(b*1024 + s*64))*1024;
  const size_t vbase = ((size_t)(b*16 + s))*512*64;
  const int myslot = w*16 + lr;
  const size_t qrow = (size_t)(rowStart + min(myslot, cnt - 1))*512;
  #pragma unroll
  for (int hh = 0; hh < 2; ++hh){
    const int h = hg*2 + hh;
    __syncthreads();                       // prior compute done reading Ks/Vs
    #pragma unroll
    for (int t = 0; t < 2; ++t){
      int ci = t*256 + tid;                // 0..511
      int r = ci >> 3, q = ci & 7;
      int qs = (q ^ (r & 7)) << 3;
      async16(kvb + kbase + (size_t)r*1024 + h*64 + qs, (char*)Ks + ci*16);
      async16(vt + vbase + (size_t)(h*64 + r)*64 + qs, (char*)Vs + ci*16);
    }
    __syncthreads();
    // Q fragments (A-operand: row = lane&15 = token slot, k = lg*8)
    bf16x8 qa0 = *(const bf16x8*)(qb + qrow + h*64 + lg*8);
    bf16x8 qa1 = *(const bf16x8*)(qb + qrow + h*64 + 32 + lg*8);
    // S = Q Kh^T
    f32x4 sv[4] = {};
    #pragma unroll
    for (int n = 0; n < 4; ++n){
      int row = n*16 + lr;
      int sl0 = (lg) ^ (row & 7);
      int sl1 = (4 + lg) ^ (row & 7);
      bf16x8 kb0 = *(const bf16x8*)((const char*)Ks + row*128 + sl0*16);
      sv[n] = __builtin_amdgcn_mfma_f32_16x16x32_bf16(qa0, kb0, sv[n], 0, 0, 0);
      bf16x8 kb1 = *(const bf16x8*)((const char*)Ks + row*128 + sl1*16);
      sv[n] = __builtin_amdgcn_mfma_f32_16x16x32_bf16(qa1, kb1, sv[n], 0, 0, 0);
    }
    // row softmax: rows 4*lg+r, spread over 16-lane group + 4 register tiles
    float inv[4];
    #pragma unroll
    for (int r = 0; r < 4; ++r){
      float m = fmaxf(fmaxf(sv[0][r], sv[1][r]), fmaxf(sv[2][r], sv[3][r]));
      #pragma unroll
      for (int o = 1; o < 16; o <<= 1) m = fmaxf(m, __shfl_xor(m, o));
      float s0 = 0.f;
      #pragma unroll
      for (int n = 0; n < 4; ++n){ sv[n][r] = __expf(sv[n][r] - m); s0 += sv[n][r]; }
      #pragma unroll
      for (int o = 1; o < 16; o <<= 1) s0 += __shfl_xor(s0, o);
      inv[r] = 1.f / s0;
    }
    // P -> LDS (wave-private) in [16 tok][72] layout
    u16* pw = &Ps[w][0];
    #pragma unroll
    for (int n = 0; n < 4; ++n)
      #pragma unroll
      for (int r = 0; r < 4; ++r)
        pw[(4*lg + r)*72 + n*16 + lr] = f2bf(sv[n][r] * inv[r]);
    // P A-fragments: row = lr, k = ks*32 + lg*8
    bf16x8 pa0 = *(const bf16x8*)((const char*)pw + lr*144 + lg*16);
    bf16x8 pa1 = *(const bf16x8*)((const char*)pw + lr*144 + 64 + lg*16);
    // O = P Vt
    f32x4 ov[4] = {};
    #pragma unroll
    for (int n = 0; n < 4; ++n){
      int row = n*16 + lr;
      int sl0 = (lg) ^ (row & 7);
      int sl1 = (4 + lg) ^ (row & 7);
      bf16x8 vb0 = *(const bf16x8*)((const char*)Vs + row*128 + sl0*16);
      ov[n] = __builtin_amdgcn_mfma_f32_16x16x32_bf16(pa0, vb0, ov[n], 0, 0, 0);
      bf16x8 vb1 = *(const bf16x8*)((const char*)Vs + row*128 + sl1*16);
      ov[n] = __builtin_amdgcn_mfma_f32_16x16x32_bf16(pa1, vb1, ov[n], 0, 0, 0);
    }
    // write O rows (guard padded slots)
    #pragma unroll
    for (int r = 0; r < 4; ++r){
      int slot = w*16 + 4*lg + r;
      if (slot < cnt){
        size_t orow = (size_t)(rowStart + slot)*512 + h*64;
        #pragma unroll
        for (int n = 0; n < 4; ++n)
          aout[orow + n*16 + lr] = f2bf(ov[n][r]);
      }
    }
  }
}

extern "C" void kernel_launch(void* const* d_in, const int* in_sizes, int n_in,
                              void* d_out, int out_size, void* d_ws, size_t ws_size,
                              hipStream_t stream){
  const void* x      = d_in[0];
  const void* media  = d_in[1];
  const void* mloc   = d_in[2];
  const void* ln_g   = d_in[3];
  const void* ln_b   = d_in[4];
  const void* Wq     = d_in[5];
  const void* Wk     = d_in[6];
  const void* Wv     = d_in[7];
  const void* Wo     = d_in[8];
  char* ws = (char*)d_ws;
  u16* xn    = (u16*)(ws + OFF_XN);
  u16* medb  = (u16*)(ws + OFF_MEDIA);
  u16* qb    = (u16*)(ws + OFF_Q);
  u16* kvb   = (u16*)(ws + OFF_KV);
  u16* aout  = (u16*)(ws + OFF_AOUT);
  u16* WqT   = (u16*)(ws + OFF_WQT);
  u16* WkvT  = (u16*)(ws + OFF_WKVT);
  u16* WoT   = (u16*)(ws + OFF_WOT);
  float* vsm = (float*)(ws + OFF_VSUM);
  int* flags = (int*)(ws + OFF_FLAGS);
  u16* vt    = (u16*)(ws + OFF_VT);
  int* bound = (int*)(ws + OFF_BOUND);
  int* nblk  = (int*)(ws + OFF_NBLK);
  int4* desc = (int4*)(ws + OFF_DESC);

  setup_kernel<<<1, 256, 0, stream>>>((const unsigned int*)x, (const uch*)mloc, flags, vsm, bound);

  wtrans_all_kernel<<<2048, dim3(32, 8), 0, stream>>>(Wq, Wk, Wv, Wo, WqT, WkvT, WoT, flags);
  ln_kernel<<<NTOK, 256, 0, stream>>>(x, ln_g, ln_b, xn, flags);
  cvt_kernel<<<4096, 256, 0, stream>>>(media, medb, flags);
  cumsum_kernel<<<BATCH, 256, 0, stream>>>(mloc, bound, flags);
  plan_kernel<<<1, 64, 0, stream>>>(bound, desc, nblk);

  // q = (xn @ Wq) * DH^-0.5
  gemm_bt<0><<<dim3(4, 128), 256, 0, stream>>>(xn, WqT, qb, NTOK, INNER, DIM, 0.125f, flags, nullptr);
  // kv = media @ [Wk | Wv], dual-writing V^T
  gemm_bt<2><<<dim3(8, 32), 256, 0, stream>>>(medb, WkvT, kvb, BATCH*KVN, 1024, DIM, 1.f, flags, vt);

  vsum_kernel<<<dim3(BATCH, 8), 512, 0, stream>>>(kvb, vsm);
  attn2_kernel<<<dim3(MAXBLK, 4), 256, 0, stream>>>(qb, kvb, vt, nblk, desc, vsm, aout);

  // out = aout @ Wo
  gemm_bt<1><<<dim3(8, 128), 256, 0, stream>>>(aout, WoT, d_out, NTOK, DIM, INNER, 1.f, flags, nullptr);
}

// Round 6
// 169.934 us; speedup vs baseline: 2.0178x; 1.0605x over previous
//
#include <hip/hip_runtime.h>

using u16 = unsigned short;
using uch = unsigned char;

typedef __bf16 bf16x8 __attribute__((ext_vector_type(8)));
typedef float f32x4 __attribute__((ext_vector_type(4)));

// ---------- constants ----------
#define BATCH 4
#define SEQN 4096
#define TT 16
#define MM 64
#define DIM 1024
#define HEADS 8
#define DH 64
#define INNER 512
#define KVN 1024
#define NTOK (BATCH*SEQN)          // 16384
#define MAXBLK 352                 // 4 * (64 + 18) upper bound on chunk count

// ws offsets (bytes)
#define OFF_XN     ((size_t)0)                     // 16384x1024 bf16 = 32MB
#define OFF_MEDIA  ((size_t)33554432)              // 4096x1024 bf16 = 8MB
#define OFF_Q      ((size_t)41943040)              // 16384x512 bf16 = 16MB
#define OFF_KV     ((size_t)58720256)              // 4096x1024 bf16 = 8MB
#define OFF_AOUT   ((size_t)67108864)              // 16384x512 bf16 = 16MB
#define OFF_WQT    ((size_t)83886080)              // 512x1024 bf16 = 1MB
#define OFF_WKVT   ((size_t)84934656)              // 1024x1024 bf16 = 2MB
#define OFF_WOT    ((size_t)87031808)              // 1024x512 bf16 = 1MB
#define OFF_VSUM   ((size_t)88145920)              // 4x512 f32 = 8KB
#define OFF_FLAGS  ((size_t)88154112)              // int[2]
#define OFF_VT     ((size_t)88155136)              // 64 groups x 512 x 64 bf16 = 4MB
#define OFF_BOUND  ((size_t)92349440)              // 4x18 int
#define OFF_NBLK   ((size_t)92350464)              // int
#define OFF_DESC   ((size_t)92351488)              // MAXBLK x int4 = 5632B

__device__ __forceinline__ u16 f2bf(float f){
  unsigned int u = __float_as_uint(f);
  u += 0x7fffu + ((u >> 16) & 1u);
  return (u16)(u >> 16);
}
__device__ __forceinline__ float bf2f(u16 b){ return __uint_as_float(((unsigned int)b) << 16); }

__device__ __forceinline__ void async16(const u16* g, void* l){
  __builtin_amdgcn_global_load_lds((__attribute__((address_space(1))) void*)(g),
                                   (__attribute__((address_space(3))) void*)(l), 16, 0, 0);
}

// ---------- setup: format detect + zero vsum + init bounds (one dispatch) ----------
__global__ void setup_kernel(const unsigned int* __restrict__ x, const uch* __restrict__ loc,
                             int* __restrict__ flags, float* __restrict__ vsum,
                             int* __restrict__ bound){
  __shared__ int cnt, nonz;
  int tid = threadIdx.x;
  if (tid == 0){ cnt = 0; nonz = 0; }
  __syncthreads();
  int c = 0;
  for (int t = 0; t < 4; ++t){
    unsigned int w = x[t*256 + tid];
    unsigned int e = (w >> 7) & 0xFFu;
    if (e >= 110u && e <= 140u) c++;
  }
  atomicAdd(&cnt, c);
  int nz = 0;
  for (int t = 0; t < 16; ++t){
    int i = t*256 + tid;
    if ((i & 3) && loc[i]) nz++;
  }
  atomicAdd(&nonz, nz);
  #pragma unroll
  for (int t = 0; t < 8; ++t) vsum[t*256 + tid] = 0.f;
  if (tid < 72) bound[tid] = 4096;
  __syncthreads();
  if (tid == 0){ flags[0] = (cnt > 512) ? 1 : 0; flags[1] = (nonz == 0) ? 1 : 0; }
}

// ---------- all 4 weight transposes in one dispatch ----------
__global__ void wtrans_all_kernel(const void* __restrict__ Wq, const void* __restrict__ Wk,
                                  const void* __restrict__ Wv, const void* __restrict__ Wo,
                                  u16* __restrict__ WqT, u16* __restrict__ WkvT, u16* __restrict__ WoT,
                                  const int* __restrict__ flags){
  const int bf = flags[0];
  __shared__ float tile[32][33];
  int id = blockIdx.x;
  const void* in; u16* out; int K, N, bx, by;
  if (id < 512){       in = Wq; out = WqT;  K = DIM;   N = INNER; int l = id;        bx = l & 15; by = l >> 4; }
  else if (id < 1024){ in = Wk; out = WkvT; K = DIM;   N = INNER; int l = id - 512;  bx = l & 15; by = l >> 4; }
  else if (id < 1536){ in = Wv; out = WkvT + (size_t)512*1024; K = DIM; N = INNER; int l = id - 1024; bx = l & 15; by = l >> 4; }
  else {               in = Wo; out = WoT;  K = INNER; N = DIM;   int l = id - 1536; bx = l & 31; by = l >> 5; }
  int n0 = bx*32, k0 = by*32;
  int tx = threadIdx.x, ty = threadIdx.y;
  #pragma unroll
  for (int i = 0; i < 4; ++i){
    size_t idx = (size_t)(k0 + ty + i*8)*N + n0 + tx;
    tile[ty + i*8][tx] = bf ? bf2f(((const u16*)in)[idx]) : ((const float*)in)[idx];
  }
  __syncthreads();
  #pragma unroll
  for (int i = 0; i < 4; ++i)
    out[(size_t)(n0 + ty + i*8)*K + k0 + tx] = f2bf(tile[tx][ty + i*8]);
}

// ---------- LayerNorm + media-convert fused (one dispatch) ----------
__global__ __launch_bounds__(256) void ln_cvt_kernel(const void* __restrict__ xp, const void* __restrict__ gp,
                          const void* __restrict__ bp, u16* __restrict__ xn,
                          const void* __restrict__ media, u16* __restrict__ medb,
                          const int* __restrict__ flags){
  const int bf = flags[0];
  const int tid = threadIdx.x;
  if ((int)blockIdx.x >= NTOK){
    // media convert: 4096 blocks x 1024 elems
    size_t i = (size_t)(blockIdx.x - NTOK)*256 + tid;
    if (bf){
      ((ushort4*)medb)[i] = ((const ushort4*)media)[i];
    } else {
      float4 t = ((const float4*)media)[i];
      ushort4 o; o.x = f2bf(t.x); o.y = f2bf(t.y); o.z = f2bf(t.z); o.w = f2bf(t.w);
      ((ushort4*)medb)[i] = o;
    }
    return;
  }
  const int row = blockIdx.x;
  float v[4];
  if (bf){
    ushort4 t = ((const ushort4*)((const u16*)xp + (size_t)row*DIM))[tid];
    v[0]=bf2f(t.x); v[1]=bf2f(t.y); v[2]=bf2f(t.z); v[3]=bf2f(t.w);
  } else {
    float4 t = ((const float4*)((const float*)xp + (size_t)row*DIM))[tid];
    v[0]=t.x; v[1]=t.y; v[2]=t.z; v[3]=t.w;
  }
  float s = v[0]+v[1]+v[2]+v[3];
  float sq = v[0]*v[0]+v[1]*v[1]+v[2]*v[2]+v[3]*v[3];
  #pragma unroll
  for (int o = 32; o > 0; o >>= 1){ s += __shfl_down(s, o); sq += __shfl_down(sq, o); }
  __shared__ float ss[4], ssq[4];
  int wid = tid >> 6, lane = tid & 63;
  if (lane == 0){ ss[wid] = s; ssq[wid] = sq; }
  __syncthreads();
  s = ss[0]+ss[1]+ss[2]+ss[3]; sq = ssq[0]+ssq[1]+ssq[2]+ssq[3];
  float mean = s * (1.f/DIM);
  float rstd = rsqrtf(sq * (1.f/DIM) - mean*mean + 1e-5f);
  float g[4], bb[4];
  if (bf){
    ushort4 t1 = ((const ushort4*)gp)[tid]; ushort4 t2 = ((const ushort4*)bp)[tid];
    g[0]=bf2f(t1.x); g[1]=bf2f(t1.y); g[2]=bf2f(t1.z); g[3]=bf2f(t1.w);
    bb[0]=bf2f(t2.x); bb[1]=bf2f(t2.y); bb[2]=bf2f(t2.z); bb[3]=bf2f(t2.w);
  } else {
    float4 t1 = ((const float4*)gp)[tid]; float4 t2 = ((const float4*)bp)[tid];
    g[0]=t1.x; g[1]=t1.y; g[2]=t1.z; g[3]=t1.w;
    bb[0]=t2.x; bb[1]=t2.y; bb[2]=t2.z; bb[3]=t2.w;
  }
  ushort4 o;
  o.x = f2bf((v[0]-mean)*rstd*g[0] + bb[0]);
  o.y = f2bf((v[1]-mean)*rstd*g[1] + bb[1]);
  o.z = f2bf((v[2]-mean)*rstd*g[2] + bb[2]);
  o.w = f2bf((v[3]-mean)*rstd*g[3] + bb[3]);
  ((ushort4*)(xn + (size_t)row*DIM))[tid] = o;
}

// ---------- cumsum + boundary detection fused ----------
__global__ __launch_bounds__(256) void cumsum_kernel(const void* __restrict__ locp, int* __restrict__ bound,
                              const int* __restrict__ flags){
  const int as32 = flags[1];
  int b = blockIdx.x, tid = threadIdx.x;
  int lane = tid & 63, wid = tid >> 6;
  __shared__ int wsum[4]; __shared__ int carry;
  if (tid == 0) carry = 0;
  __syncthreads();
  for (int t = 0; t < 16; ++t){
    int idx = t*256 + tid;
    int v;
    if (as32) v = (((const int*)locp)[b*SEQN + idx] != 0);
    else      v = (((const uch*)locp)[b*SEQN + idx] != 0);
    int s = v;
    #pragma unroll
    for (int o = 1; o < 64; o <<= 1){ int n = __shfl_up(s, o); if (lane >= o) s += n; }
    if (lane == 63) wsum[wid] = s;
    __syncthreads();
    int wo = carry;
    for (int w = 0; w < wid; ++w) wo += wsum[w];
    int tt = wo + s;
    if (v && tt <= 17) bound[b*18 + tt] = idx;
    __syncthreads();
    if (tid == 0) carry += wsum[0] + wsum[1] + wsum[2] + wsum[3];
    __syncthreads();
  }
}

// ---------- plan: contiguous ranges -> chunk descriptors ----------
__global__ void plan_kernel(const int* __restrict__ bound, int4* __restrict__ desc,
                            int* __restrict__ nblk){
  if (threadIdx.x != 0) return;
  int n = 0;
  for (int b = 0; b < BATCH; ++b){
    int bnd[19];
    bnd[0] = 0;
    for (int g = 1; g <= 17; ++g) bnd[g] = bound[b*18 + g];
    bnd[18] = 4096;
    for (int g = 0; g <= 17; ++g){
      int lo = bnd[g];
      int hi = (g < 17) ? bnd[g+1] : 4096;
      if (lo >= 4096) lo = 4096;
      int s = (g == 0 || g == 17) ? -1 : (g - 1);
      for (int k = lo; k < hi; k += 64){
        int4 d; d.x = b; d.y = s; d.z = b*4096 + k; d.w = min(64, hi - k);
        desc[n++] = d;
      }
    }
  }
  *nblk = n;
}

// ---------- V column sums (uniform-softmax fallback) ----------
__global__ __launch_bounds__(512) void vsum_kernel(const u16* __restrict__ kv, float* __restrict__ vsum){
  int b = blockIdx.x, ch = blockIdx.y, c = threadIdx.x;
  size_t base = ((size_t)b*KVN + ch*128)*1024 + 512 + c;
  float s = 0.f;
  for (int r = 0; r < 128; ++r) s += bf2f(kv[base + (size_t)r*1024]);
  atomicAdd(&vsum[b*512 + c], s);
}

// ---------- 128-tile GEMM (q-proj, kv-proj): C = alpha * A @ Bt^T ----------
// MODE 0: C bf16.  MODE 2: C bf16 + dual-write V^T.
template<int MODE>
__global__ __launch_bounds__(256) void gemm_bt(const u16* __restrict__ A, const u16* __restrict__ Bt,
                        void* __restrict__ Cp, int M, int N, int K, float alpha,
                        const int* __restrict__ flags, u16* __restrict__ vtp){
  __shared__ u16 As[128*64];
  __shared__ u16 Bs[128*64];
  const int tid = threadIdx.x, wid = tid >> 6, lane = tid & 63;
  int flat = blockIdx.x + blockIdx.y*gridDim.x;
  int cpx = (gridDim.x*gridDim.y) >> 3;
  int wg = (flat & 7)*cpx + (flat >> 3);
  const int rn = wg % gridDim.x, rm = wg / gridDim.x;
  const int wr = wid >> 1, wc = wid & 1;
  const int lr = lane & 15, lg = lane >> 4;
  f32x4 acc[4][4] = {};
  const u16* Ab = A + (size_t)rm*128*K;
  const u16* Bb = Bt + (size_t)rn*128*K;
  for (int k0 = 0; k0 < K; k0 += 64){
    __syncthreads();
    #pragma unroll
    for (int t = 0; t < 4; ++t){
      int c = t*256 + tid;
      int row = c >> 3;
      int qs = (c & 7) ^ (row & 7);
      int ldsOff = (t*256 + wid*64) * 16;
      async16(Ab + (size_t)row*K + k0 + qs*8, (char*)As + ldsOff);
      async16(Bb + (size_t)row*K + k0 + qs*8, (char*)Bs + ldsOff);
    }
    __syncthreads();
    #pragma unroll
    for (int ks = 0; ks < 2; ++ks){
      bf16x8 af[4], bfr[4];
      #pragma unroll
      for (int m = 0; m < 4; ++m){
        int row = wr*64 + m*16 + lr;
        int q = (ks*4 + lg) ^ (row & 7);
        af[m] = *(const bf16x8*)((const char*)As + row*128 + (q << 4));
      }
      #pragma unroll
      for (int n = 0; n < 4; ++n){
        int row = wc*64 + n*16 + lr;
        int q = (ks*4 + lg) ^ (row & 7);
        bfr[n] = *(const bf16x8*)((const char*)Bs + row*128 + (q << 4));
      }
      #pragma unroll
      for (int m = 0; m < 4; ++m)
        #pragma unroll
        for (int n = 0; n < 4; ++n)
          acc[m][n] = __builtin_amdgcn_mfma_f32_16x16x32_bf16(af[m], bfr[n], acc[m][n], 0, 0, 0);
    }
  }
  #pragma unroll
  for (int m = 0; m < 4; ++m){
    #pragma unroll
    for (int n = 0; n < 4; ++n){
      int row0 = rm*128 + wr*64 + m*16 + lg*4;
      int col  = rn*128 + wc*64 + n*16 + lr;
      #pragma unroll
      for (int r = 0; r < 4; ++r){
        float v = acc[m][n][r] * alpha;
        size_t idx = (size_t)(row0 + r)*N + col;
        u16 bv = f2bf(v);
        ((u16*)Cp)[idx] = bv;
        if (MODE == 2 && col >= 512){
          int row = row0 + r;
          int b = row >> 10, kvi = row & 1023;
          int s = kvi >> 6, rr = kvi & 63;
          vtp[((size_t)((b*16 + s)*512 + (col - 512)))*64 + rr] = bv;
        }
      }
    }
  }
}

// ---------- 8-phase 256x256 GEMM for out-proj: d_out = aout @ WoT^T ----------
// M=16384, N=1024, K=512. grid (4, 64), 512 threads (8 waves, 2M x 4N).
#define G8_K 512
#define G8_N 1024
#define G8_NT 8
__global__ __launch_bounds__(512, 2) void gemm8_out(const u16* __restrict__ A, const u16* __restrict__ Bt,
                        void* __restrict__ Cp, const int* __restrict__ flags){
  __shared__ u16 As[2][256*64];
  __shared__ u16 Bs[2][256*64];
  const int tid = threadIdx.x, wid = tid >> 6, lane = tid & 63;
  int flat = blockIdx.x + blockIdx.y*gridDim.x;
  int cpx = (gridDim.x*gridDim.y) >> 3;
  int wg = (flat & 7)*cpx + (flat >> 3);
  const int rn = wg % gridDim.x, rm = wg / gridDim.x;
  const int wr = wid >> 2, wc = wid & 3;     // 2 x 4 wave grid
  const int lr = lane & 15, lg = lane >> 4;
  f32x4 acc[8][4] = {};
  const u16* Ab = A + (size_t)rm*256*G8_K;
  const u16* Bb = Bt + (size_t)rn*256*G8_K;

  // stage one 256x64 tile (4 issues x 512 thr x 16B = 32KB), pre-swizzled source
  #define G8_STAGE(src, dst, t)                                                  \
    _Pragma("unroll")                                                            \
    for (int i_ = 0; i_ < 4; ++i_){                                              \
      int s_ = i_*512 + tid;                                                     \
      int row_ = s_ >> 3, g_ = s_ & 7;                                           \
      async16((src) + (size_t)row_*G8_K + (t)*64 + ((g_ ^ (row_ & 7)) << 3),     \
              (char*)(dst) + (i_*512 + wid*64)*16);                              \
    }

  G8_STAGE(Ab, As[0], 0)
  G8_STAGE(Bb, Bs[0], 0)
  __syncthreads();                       // vmcnt(0) + barrier: tile 0 resident

  for (int t = 0; t < G8_NT; ++t){
    const int cur = t & 1;
    const char* Acur = (const char*)As[cur];
    const char* Bcur = (const char*)Bs[cur];
    bf16x8 bfr[4][2];
    #pragma unroll
    for (int p = 0; p < 4; ++p){
      if (p == 0 && t + 1 < G8_NT){      // issue ALL next-tile prefetch early
        G8_STAGE(Ab, As[cur^1], t+1)
        G8_STAGE(Bb, Bs[cur^1], t+1)
      }
      bf16x8 af[2][2];
      #pragma unroll
      for (int i = 0; i < 2; ++i){
        int row = wr*128 + (2*p + i)*16 + lr;
        #pragma unroll
        for (int ks = 0; ks < 2; ++ks){
          int g = (ks*4 + lg) ^ (row & 7);
          af[i][ks] = *(const bf16x8*)(Acur + row*128 + g*16);
        }
      }
      if (p == 0){
        #pragma unroll
        for (int n = 0; n < 4; ++n){
          int row = wc*64 + n*16 + lr;
          #pragma unroll
          for (int ks = 0; ks < 2; ++ks){
            int g = (ks*4 + lg) ^ (row & 7);
            bfr[n][ks] = *(const bf16x8*)(Bcur + row*128 + g*16);
          }
        }
      }
      __builtin_amdgcn_s_barrier();
      __builtin_amdgcn_s_setprio(1);
      #pragma unroll
      for (int i = 0; i < 2; ++i)
        #pragma unroll
        for (int n = 0; n < 4; ++n)
          #pragma unroll
          for (int ks = 0; ks < 2; ++ks)
            acc[2*p + i][n] = __builtin_amdgcn_mfma_f32_16x16x32_bf16(af[i][ks], bfr[n][ks], acc[2*p + i][n], 0, 0, 0);
      __builtin_amdgcn_s_setprio(0);
      __builtin_amdgcn_s_barrier();
    }
    if (t + 1 < G8_NT) __syncthreads();  // vmcnt(0)+barrier: next tile resident, old buf free
  }

  const bool obf = flags[0] != 0;
  #pragma unroll
  for (int m = 0; m < 8; ++m){
    #pragma unroll
    for (int n = 0; n < 4; ++n){
      int row0 = rm*256 + wr*128 + m*16 + lg*4;
      int col  = rn*256 + wc*64 + n*16 + lr;
      #pragma unroll
      for (int r = 0; r < 4; ++r){
        float v = acc[m][n][r];
        size_t idx = (size_t)(row0 + r)*G8_N + col;
        if (obf) ((u16*)Cp)[idx] = f2bf(v);
        else     ((float*)Cp)[idx] = v;
      }
    }
  }
}

// ---------- grouped masked attention: 1 head per block ----------
// grid (MAXBLK, 8): blockIdx.y = head.
__global__ __launch_bounds__(256) void attn2_kernel(
    const u16* __restrict__ qb, const u16* __restrict__ kvb, const u16* __restrict__ vt,
    const int* __restrict__ nblk, const int4* __restrict__ desc,
    const float* __restrict__ vsum, u16* __restrict__ aout){
  __shared__ u16 Ks[64*64];
  __shared__ u16 Vs[64*64];
  __shared__ u16 Ps[4][16*72];     // pad to 72 (144B rows, 16B-aligned)
  if (blockIdx.x >= *nblk) return;
  const int4 d = desc[blockIdx.x];
  const int b = d.x, s = d.y, rowStart = d.z, cnt = d.w;
  const int h = blockIdx.y;
  const int tid = threadIdx.x, w = tid >> 6, lane = tid & 63;
  if (s < 0){
    // uniform softmax over all KV -> mean of V; this block owns cols [h*64, h*64+64)
    const float inv = 1.f/1024.f;
    for (int idx = tid; idx < cnt*64; idx += 256){
      int slot = idx >> 6, c = h*64 + (idx & 63);
      aout[(size_t)(rowStart + slot)*512 + c] = f2bf(vsum[b*512 + c]*inv);
    }
    return;
  }
  const int lr = lane & 15, lg = lane >> 4;
  const size_t kbase = ((size_t)(b*1024 + s*64))*1024;
  const size_t vbase = ((size_t)(b*16 + s))*512*64;
  const int myslot = w*16 + lr;
  const size_t qrow = (size_t)(rowStart + min(myslot, cnt - 1))*512;
  #pragma unroll
  for (int t = 0; t < 2; ++t){
    int ci = t*256 + tid;                // 0..511
    int r = ci >> 3, q = ci & 7;
    int qs = (q ^ (r & 7)) << 3;
    async16(kvb + kbase + (size_t)r*1024 + h*64 + qs, (char*)Ks + ci*16);
    async16(vt + vbase + (size_t)(h*64 + r)*64 + qs, (char*)Vs + ci*16);
  }
  __syncthreads();
  bf16x8 qa0 = *(const bf16x8*)(qb + qrow + h*64 + lg*8);
  bf16x8 qa1 = *(const bf16x8*)(qb + qrow + h*64 + 32 + lg*8);
  // S = Q Kh^T
  f32x4 sv[4] = {};
  #pragma unroll
  for (int n = 0; n < 4; ++n){
    int row = n*16 + lr;
    int sl0 = (lg) ^ (row & 7);
    int sl1 = (4 + lg) ^ (row & 7);
    bf16x8 kb0 = *(const bf16x8*)((const char*)Ks + row*128 + sl0*16);
    sv[n] = __builtin_amdgcn_mfma_f32_16x16x32_bf16(qa0, kb0, sv[n], 0, 0, 0);
    bf16x8 kb1 = *(const bf16x8*)((const char*)Ks + row*128 + sl1*16);
    sv[n] = __builtin_amdgcn_mfma_f32_16x16x32_bf16(qa1, kb1, sv[n], 0, 0, 0);
  }
  // row softmax
  float inv[4];
  #pragma unroll
  for (int r = 0; r < 4; ++r){
    float m = fmaxf(fmaxf(sv[0][r], sv[1][r]), fmaxf(sv[2][r], sv[3][r]));
    #pragma unroll
    for (int o = 1; o < 16; o <<= 1) m = fmaxf(m, __shfl_xor(m, o));
    float s0 = 0.f;
    #pragma unroll
    for (int n = 0; n < 4; ++n){ sv[n][r] = __expf(sv[n][r] - m); s0 += sv[n][r]; }
    #pragma unroll
    for (int o = 1; o < 16; o <<= 1) s0 += __shfl_xor(s0, o);
    inv[r] = 1.f / s0;
  }
  // P -> LDS (wave-private) in [16 tok][72] layout
  u16* pw = &Ps[w][0];
  #pragma unroll
  for (int n = 0; n < 4; ++n)
    #pragma unroll
    for (int r = 0; r < 4; ++r)
      pw[(4*lg + r)*72 + n*16 + lr] = f2bf(sv[n][r] * inv[r]);
  bf16x8 pa0 = *(const bf16x8*)((const char*)pw + lr*144 + lg*16);
  bf16x8 pa1 = *(const bf16x8*)((const char*)pw + lr*144 + 64 + lg*16);
  // O = P Vt
  f32x4 ov[4] = {};
  #pragma unroll
  for (int n = 0; n < 4; ++n){
    int row = n*16 + lr;
    int sl0 = (lg) ^ (row & 7);
    int sl1 = (4 + lg) ^ (row & 7);
    bf16x8 vb0 = *(const bf16x8*)((const char*)Vs + row*128 + sl0*16);
    ov[n] = __builtin_amdgcn_mfma_f32_16x16x32_bf16(pa0, vb0, ov[n], 0, 0, 0);
    bf16x8 vb1 = *(const bf16x8*)((const char*)Vs + row*128 + sl1*16);
    ov[n] = __builtin_amdgcn_mfma_f32_16x16x32_bf16(pa1, vb1, ov[n], 0, 0, 0);
  }
  #pragma unroll
  for (int r = 0; r < 4; ++r){
    int slot = w*16 + 4*lg + r;
    if (slot < cnt){
      size_t orow = (size_t)(rowStart + slot)*512 + h*64;
      #pragma unroll
      for (int n = 0; n < 4; ++n)
        aout[orow + n*16 + lr] = f2bf(ov[n][r]);
    }
  }
}

extern "C" void kernel_launch(void* const* d_in, const int* in_sizes, int n_in,
                              void* d_out, int out_size, void* d_ws, size_t ws_size,
                              hipStream_t stream){
  const void* x      = d_in[0];
  const void* media  = d_in[1];
  const void* mloc   = d_in[2];
  const void* ln_g   = d_in[3];
  const void* ln_b   = d_in[4];
  const void* Wq     = d_in[5];
  const void* Wk     = d_in[6];
  const void* Wv     = d_in[7];
  const void* Wo     = d_in[8];
  char* ws = (char*)d_ws;
  u16* xn    = (u16*)(ws + OFF_XN);
  u16* medb  = (u16*)(ws + OFF_MEDIA);
  u16* qb    = (u16*)(ws + OFF_Q);
  u16* kvb   = (u16*)(ws + OFF_KV);
  u16* aout  = (u16*)(ws + OFF_AOUT);
  u16* WqT   = (u16*)(ws + OFF_WQT);
  u16* WkvT  = (u16*)(ws + OFF_WKVT);
  u16* WoT   = (u16*)(ws + OFF_WOT);
  float* vsm = (float*)(ws + OFF_VSUM);
  int* flags = (int*)(ws + OFF_FLAGS);
  u16* vt    = (u16*)(ws + OFF_VT);
  int* bound = (int*)(ws + OFF_BOUND);
  int* nblk  = (int*)(ws + OFF_NBLK);
  int4* desc = (int4*)(ws + OFF_DESC);

  setup_kernel<<<1, 256, 0, stream>>>((const unsigned int*)x, (const uch*)mloc, flags, vsm, bound);

  wtrans_all_kernel<<<2048, dim3(32, 8), 0, stream>>>(Wq, Wk, Wv, Wo, WqT, WkvT, WoT, flags);
  ln_cvt_kernel<<<NTOK + 4096, 256, 0, stream>>>(x, ln_g, ln_b, xn, media, medb, flags);
  cumsum_kernel<<<BATCH, 256, 0, stream>>>(mloc, bound, flags);
  plan_kernel<<<1, 64, 0, stream>>>(bound, desc, nblk);

  // q = (xn @ Wq) * DH^-0.5
  gemm_bt<0><<<dim3(4, 128), 256, 0, stream>>>(xn, WqT, qb, NTOK, INNER, DIM, 0.125f, flags, nullptr);
  // kv = media @ [Wk | Wv], dual-writing V^T
  gemm_bt<2><<<dim3(8, 32), 256, 0, stream>>>(medb, WkvT, kvb, BATCH*KVN, 1024, DIM, 1.f, flags, vt);

  vsum_kernel<<<dim3(BATCH, 8), 512, 0, stream>>>(kvb, vsm);
  attn2_kernel<<<dim3(MAXBLK, 8), 256, 0, stream>>>(qb, kvb, vt, nblk, desc, vsm, aout);

  // out = aout @ Wo  (8-phase 256^2)
  gemm8_out<<<dim3(4, 64), 512, 0, stream>>>(aout, WoT, d_out, flags);
}